// Round 5
// baseline (393.970 us; speedup 1.0000x reference)
//
#include <hip/hip_runtime.h>

// ---------------------------------------------------------------------------
// MultiHeadAttention (B=1, N=2925, D_MODEL=1536, 12 heads x 128) on gfx950.
// convert/transpose -> fused QKV bf16-MFMA GEMM (global_load_lds staging) ->
// RMSNorm+3D RoPE (exp2-domain q-scale) -> V transpose -> split-KV flash
// attention (swapped-QK^T, 2 waves x 32 q-rows, phase-shifted async staging,
// counted vmcnt, raw barriers, XCD swizzle, setprio) -> combine -> O GEMM.
// ---------------------------------------------------------------------------

#define N_TOK 2925
#define DMODEL 1536
#define NHEAD 12
#define HDIM 128
#define KSPLIT 1472           // split-KV boundary (23 tiles of 64)
#define VT_STRIDE 2944        // N_TOK padded to x64; pad MUST be zeroed (NaN hazard)

typedef __attribute__((ext_vector_type(8))) __bf16 bf16x8;
typedef __attribute__((ext_vector_type(4))) float floatx4;

#define MFMA(a, b, c) __builtin_amdgcn_mfma_f32_16x16x32_bf16((a), (b), (c), 0, 0, 0)

static __device__ __forceinline__ unsigned short f2bf(float f) {
    unsigned u = __builtin_bit_cast(unsigned, f);
    return (unsigned short)((u + 0x7fffu + ((u >> 16) & 1u)) >> 16);
}

// async global->LDS 16B/lane (emits global_load_lds_dwordx4).
// LDS dest MUST be wave-uniform-base + lane*16.
static __device__ __forceinline__ void gload_lds16(const unsigned short* g, unsigned short* l) {
    __builtin_amdgcn_global_load_lds((const __attribute__((address_space(1))) void*)g,
                                     (__attribute__((address_space(3))) void*)l, 16, 0, 0);
}

// ---------------------------------------------------------------- convert x
__global__ __launch_bounds__(256) void k_convert_x(const float* __restrict__ x,
                                                   unsigned short* __restrict__ xb, int n) {
    int i = (blockIdx.x * 256 + threadIdx.x) * 4;
    if (i < n) {
        float4 v = *(const float4*)(x + i);
        uint2 o;
        o.x = (unsigned)f2bf(v.x) | ((unsigned)f2bf(v.y) << 16);
        o.y = (unsigned)f2bf(v.z) | ((unsigned)f2bf(v.w) << 16);
        *(uint2*)(xb + i) = o;
    }
}

// ---------------------------------------------- transpose W [k][n] -> Wt [n][k] bf16
__global__ __launch_bounds__(256) void k_transpose_w(const float* __restrict__ W0,
                                                     const float* __restrict__ W1,
                                                     const float* __restrict__ W2,
                                                     const float* __restrict__ W3,
                                                     unsigned short* __restrict__ Wt) {
    __shared__ float tile[32][33];
    const float* W = blockIdx.z == 0 ? W0 : blockIdx.z == 1 ? W1 : blockIdx.z == 2 ? W2 : W3;
    unsigned short* out = Wt + (size_t)blockIdx.z * DMODEL * DMODEL;
    int tx = threadIdx.x, ty = threadIdx.y;           // 32 x 8
    int bx = blockIdx.x * 32, by = blockIdx.y * 32;
#pragma unroll
    for (int i = 0; i < 4; i++)
        tile[ty + 8 * i][tx] = W[(size_t)(by + ty + 8 * i) * DMODEL + bx + tx];
    __syncthreads();
#pragma unroll
    for (int i = 0; i < 4; i++)
        out[(size_t)(bx + ty + 8 * i) * DMODEL + by + tx] = f2bf(tile[tx][ty + 8 * i]);
}

// ------------------------------------------------------------ bf16 MFMA GEMM
// m97 structure: unpadded stride-32 LDS tiles staged via global_load_lds(16B).
__global__ __launch_bounds__(256, 2) void k_gemm(const unsigned short* __restrict__ A,
                                                 const unsigned short* __restrict__ BtBase,
                                                 const float* __restrict__ b0,
                                                 const float* __restrict__ b1,
                                                 const float* __restrict__ b2,
                                                 float* __restrict__ Cbase, int M) {
    const int z = blockIdx.z;
    const unsigned short* Bt = BtBase + (size_t)z * DMODEL * DMODEL;
    const float* bias = (z == 0) ? b0 : (z == 1) ? b1 : b2;
    float* C = Cbase + (size_t)z * M * DMODEL;

    __shared__ __align__(16) unsigned short As[128 * 32];   // [row][k], contiguous
    __shared__ __align__(16) unsigned short Bs[128 * 32];   // [n][k],   contiguous

    const int tid = threadIdx.x;
    const int wave = tid >> 6, lane = tid & 63, quad = lane >> 4, l16 = lane & 15;
    const int wr = wave >> 1, wc = wave & 1;
    const int m0 = blockIdx.y * 128, n0 = blockIdx.x * 128;

    // staging coords: thread covers row r4 (+64 on 2nd issue), 16B col chunk c4
    const int r4 = tid >> 2, c4 = (tid & 3) * 8;
    // NOTE: A rows m0+r4(+64) may exceed M (max 2943 > 2924): reads land in the
    // next ws region (no fault); garbage only reaches acc rows discarded by rg<M.

    floatx4 acc[4][4] = {};

    for (int k0 = 0; k0 < DMODEL; k0 += 32) {
        gload_lds16(A + (size_t)(m0 + r4) * DMODEL + k0 + c4,       &As[r4 * 32 + c4]);
        gload_lds16(A + (size_t)(m0 + r4 + 64) * DMODEL + k0 + c4,  &As[(r4 + 64) * 32 + c4]);
        gload_lds16(Bt + (size_t)(n0 + r4) * DMODEL + k0 + c4,      &Bs[r4 * 32 + c4]);
        gload_lds16(Bt + (size_t)(n0 + r4 + 64) * DMODEL + k0 + c4, &Bs[(r4 + 64) * 32 + c4]);
        __syncthreads();

        bf16x8 af[4], bfm[4];
#pragma unroll
        for (int i = 0; i < 4; i++)
            af[i] = *(const bf16x8*)&As[(wr * 64 + i * 16 + l16) * 32 + quad * 8];
#pragma unroll
        for (int j = 0; j < 4; j++)
            bfm[j] = *(const bf16x8*)&Bs[(wc * 64 + j * 16 + l16) * 32 + quad * 8];
#pragma unroll
        for (int i = 0; i < 4; i++)
#pragma unroll
            for (int j = 0; j < 4; j++)
                acc[i][j] = MFMA(af[i], bfm[j], acc[i][j]);
        __syncthreads();
    }

#pragma unroll
    for (int j = 0; j < 4; j++) {
        int cg = n0 + wc * 64 + j * 16 + l16;
        float bv = bias[cg];
#pragma unroll
        for (int i = 0; i < 4; i++) {
            int rbase = m0 + wr * 64 + i * 16 + quad * 4;
#pragma unroll
            for (int r = 0; r < 4; r++) {
                int rg = rbase + r;
                if (rg < M) C[(size_t)rg * DMODEL + cg] = acc[i][j][r] + bv;
            }
        }
    }
}

// ---------------------------------- fused RMSNorm (full 1536) + 3D RoPE + pack
// q pre-scaled by (1/sqrt(HDIM))*log2(e) -> softmax runs in exp2 domain.
__global__ __launch_bounds__(256) void k_norm_rope(const float* __restrict__ Qf,
                                                   const float* __restrict__ Kf,
                                                   const float* __restrict__ Vf,
                                                   const float* __restrict__ qsc,
                                                   const float* __restrict__ ksc,
                                                   const float* __restrict__ ft,
                                                   const float* __restrict__ fh,
                                                   const float* __restrict__ fw,
                                                   unsigned short* __restrict__ qb,
                                                   unsigned short* __restrict__ kb,
                                                   unsigned short* __restrict__ vb) {
    const int n = blockIdx.x;
    const int tid = threadIdx.x, wave = tid >> 6, lane = tid & 63;
    const int t_i = n / 225, rem = n % 225, h_i = rem / 15, w_i = rem % 15;
    const float att_scale = 0.08838834764831845f * 1.4426950408889634f;  // 1/sqrt(128)*log2e

    float2 qv[3], kv[3], vv[3];
    float sq = 0.f, sk = 0.f;
#pragma unroll
    for (int c = 0; c < 3; c++) {
        int p = tid + 256 * c;
        qv[c] = *(const float2*)(Qf + (size_t)n * DMODEL + 2 * p);
        kv[c] = *(const float2*)(Kf + (size_t)n * DMODEL + 2 * p);
        vv[c] = *(const float2*)(Vf + (size_t)n * DMODEL + 2 * p);
        sq += qv[c].x * qv[c].x + qv[c].y * qv[c].y;
        sk += kv[c].x * kv[c].x + kv[c].y * kv[c].y;
    }
#pragma unroll
    for (int off = 32; off >= 1; off >>= 1) {
        sq += __shfl_xor(sq, off, 64);
        sk += __shfl_xor(sk, off, 64);
    }
    __shared__ float red[2][4];
    if (lane == 0) { red[0][wave] = sq; red[1][wave] = sk; }
    __syncthreads();
    sq = red[0][0] + red[0][1] + red[0][2] + red[0][3];
    sk = red[1][0] + red[1][1] + red[1][2] + red[1][3];
    const float rq = rsqrtf(sq * (1.f / 1536.f) + 1e-6f) * att_scale;
    const float rk = rsqrtf(sk * (1.f / 1536.f) + 1e-6f);

#pragma unroll
    for (int c = 0; c < 3; c++) {
        int p = tid + 256 * c;
        int hd = p >> 6, pl = p & 63, dd = 2 * pl;
        float cs, sn;
        if (pl < 22)      { cs = ft[t_i * 44 + 2 * pl];        sn = ft[t_i * 44 + 2 * pl + 1]; }
        else if (pl < 43) { int pp = pl - 22; cs = fh[h_i * 42 + 2 * pp]; sn = fh[h_i * 42 + 2 * pp + 1]; }
        else              { int pp = pl - 43; cs = fw[w_i * 42 + 2 * pp]; sn = fw[w_i * 42 + 2 * pp + 1]; }
        int hidx = hd * 128 + dd;
        float q0 = qv[c].x * rq * qsc[hidx], q1 = qv[c].y * rq * qsc[hidx + 1];
        float k0 = kv[c].x * rk * ksc[hidx], k1 = kv[c].y * rk * ksc[hidx + 1];
        size_t o = ((size_t)hd * N_TOK + n) * HDIM + dd;
        unsigned qo = (unsigned)f2bf(q0 * cs - q1 * sn) | ((unsigned)f2bf(q0 * sn + q1 * cs) << 16);
        unsigned ko = (unsigned)f2bf(k0 * cs - k1 * sn) | ((unsigned)f2bf(k0 * sn + k1 * cs) << 16);
        unsigned vo = (unsigned)f2bf(vv[c].x) | ((unsigned)f2bf(vv[c].y) << 16);
        *(unsigned*)(qb + o) = qo;
        *(unsigned*)(kb + o) = ko;
        *(unsigned*)(vb + o) = vo;
    }
}

// ----------------- transpose V: [head][tok][128] -> [head][128][VT_STRIDE] bf16
// Pad columns [N_TOK, VT_STRIDE) are WRITTEN AS ZERO (recycled region NaN hazard).
__global__ __launch_bounds__(256) void k_transpose_v(const unsigned short* __restrict__ vbi,
                                                     unsigned short* __restrict__ vt) {
    __shared__ unsigned short tile[32][33];
    const int head = blockIdx.z;
    const int t0 = blockIdx.x * 32, d0 = blockIdx.y * 32;
    const int tx = threadIdx.x, ty = threadIdx.y;      // 32 x 8
#pragma unroll
    for (int i = 0; i < 4; i++) {
        int t = t0 + ty + 8 * i;
        tile[ty + 8 * i][tx] = (t < N_TOK) ? vbi[((size_t)head * N_TOK + t) * HDIM + d0 + tx] : 0;
    }
    __syncthreads();
    int t = t0 + tx;                                   // < VT_STRIDE always
#pragma unroll
    for (int i = 0; i < 4; i++)
        vt[((size_t)head * HDIM + d0 + ty + 8 * i) * VT_STRIDE + t] = tile[tx][ty + 8 * i];
}

// ---- split-KV flash attention, 2 waves x 32 q-rows, async pipeline (R8)
// Block = (q-tile 64 rows, head, split) with 128 THREADS (2 waves); each wave
// owns TWO 16-row Q-sets (q0w+l16 and q0w+16+l16).  KV tiles of 64 keys.
// Rationale: K/V LDS fragments are read ONCE per wave and feed BOTH Q-sets'
// MFMAs -> LDS-read per FLOP halves vs 4x16 (the R4 profile was LDS-bound:
// ~67us of ds_read_b128 pipe time at 36 reads/tile-wave x 101K tile-waves).
//
// Pipeline (counted vmcnt, raw barriers, NO extra LDS):
//   top:   vmcnt(8) [drain Q+K(t), V(t) in flight] ; barrier ; QK both sets
//   post-QK barrier ; issue K(t+1)
//   pre-PV: vmcnt(8) [drain V(t), K(t+1) in flight] ; barrier ; PV both sets
//   post-PV barrier ; issue V(t+1)
// exp2-domain softmax (log2e folded into q), swapped QK^T: sa[j][r] =
// S[qrow=l16(+16)][key=j*16+quad*4+r] -> lane-local softmax, b64 P writes.
// XCD swizzle: 1104 blocks = 8 x 138 (bijective).
// LDS = 16384 (K) + 16384 (V^T) + 8192 (P: 2 waves x 2 sets) = 40960
//   -> 4 blocks/CU (8 waves/CU); launch_bounds(128,2) -> VGPR cap 256.
__global__ __launch_bounds__(128, 2) void k_attn_part(const unsigned short* __restrict__ qb,
                                                      const unsigned short* __restrict__ kb,
                                                      const unsigned short* __restrict__ vt,
                                                      float* __restrict__ Opart,
                                                      float* __restrict__ mbuf,
                                                      float* __restrict__ lbuf) {
    __shared__ __align__(16) unsigned short Ks[64 * 128];    // [key][d]   linear+swz
    __shared__ __align__(16) unsigned short Vs[128 * 64];    // [d][key]   linear+swz
    __shared__ __align__(16) unsigned short Ps[2][2][16 * 64]; // [wave][set][qrow][key]

    // XCD-aware remap (bijective: 1104 = 8*138)
    const int b = blockIdx.x + 46 * (blockIdx.y + 12 * (int)blockIdx.z);
    const int w = (b & 7) * 138 + (b >> 3);
    const int qblk = w % 46;
    const int head = (w / 46) % 12;
    const int z    = w / 552;

    const int tid = threadIdx.x, wave = tid >> 6, lane = tid & 63;
    const int quad = lane >> 4, l16 = lane & 15, x7 = l16 & 7;
    const int q0w = qblk * 64 + wave * 32;     // this wave's first q-row
    const unsigned short* qh = qb + (size_t)head * N_TOK * HDIM;
    const unsigned short* kh = kb + (size_t)head * N_TOK * HDIM;
    const unsigned short* vh = vt + (size_t)head * HDIM * VT_STRIDE;
    unsigned short* ps0 = Ps[wave][0];
    unsigned short* ps1 = Ps[wave][1];

    const int kbeg = z ? KSPLIT : 0;
    const int kend = z ? N_TOK : KSPLIT;
    const int ntile = (kend - kbeg + 63) >> 6;

    // swizzled 16B-chunk read offsets (in shorts); chunk c = ks*4+quad, row&7 = l16&7.
    int koff[4];
#pragma unroll
    for (int ks = 0; ks < 4; ks++) {
        int c = ks * 4 + quad;
        koff[ks] = ((c & 8) | ((c & 7) ^ x7)) * 8;
    }
    // P write base: row l16, chunk (j*2 + (quad>>1)) ^ x7, half (quad&1).
    const int pwq = (quad >> 1), pwh = (quad & 1) * 4;

    // staging: thread covers LDS chunk (tid + 128*i), i=0..7 (lane-linear dest).
    // K:  chunk = row*16 + s  (row = (tid>>4)+8i, s = tid&15); (row&7) invariant in i
    // V^T: chunk = d*8 + s    (d = (tid>>3)+16i, s = tid&7);   (d&7)  invariant in i
    const int krow0 = tid >> 4, ksw = tid & 15;
    const int kc = (ksw & 8) | ((ksw & 7) ^ (krow0 & 7));
    const int vd0 = tid >> 3, vsw = tid & 7;
    const int vc = vsw ^ (vd0 & 7);
    const unsigned short* ksrc = kh + (size_t)krow0 * HDIM + kc * 8;
    const unsigned short* vsrc = vh + (size_t)vd0 * VT_STRIDE + vc * 8;

    // Q fragments, two row-sets (loaded FIRST: oldest vmcnt entries)
    bf16x8 aq0[4], aq1[4];
    {
        int qrow = q0w + l16;
        if (qrow < N_TOK) {
#pragma unroll
            for (int ks = 0; ks < 4; ks++)
                aq0[ks] = *(const bf16x8*)&qh[(size_t)qrow * HDIM + ks * 32 + quad * 8];
        } else {
#pragma unroll
            for (int ks = 0; ks < 4; ks++) aq0[ks] = (bf16x8)(__bf16)0.0f;
        }
        int qrow1 = q0w + 16 + l16;
        if (qrow1 < N_TOK) {
#pragma unroll
            for (int ks = 0; ks < 4; ks++)
                aq1[ks] = *(const bf16x8*)&qh[(size_t)qrow1 * HDIM + ks * 32 + quad * 8];
        } else {
#pragma unroll
            for (int ks = 0; ks < 4; ks++) aq1[ks] = (bf16x8)(__bf16)0.0f;
        }
    }

    floatx4 oacc0[8] = {}, oacc1[8] = {};
    float m_l0 = -1e30f, m_l1 = -1e30f;
    float l_l0 = 0.f, l_l1 = 0.f;    // per-lane PARTIAL sums (reduced over quads at end)

    // ---- prologue: issue K(0) then V(0)  (8 loads each per thread)
    {
        const bool part0 = (kbeg + 64 > kend);
        if (!part0) {
#pragma unroll
            for (int i = 0; i < 8; i++)
                gload_lds16(ksrc + (size_t)(kbeg + 8 * i) * HDIM, &Ks[(tid + 128 * i) * 8]);
        } else {
#pragma unroll
            for (int i = 0; i < 8; i++) {
                int gk = kbeg + krow0 + 8 * i;
                gk = gk < N_TOK ? gk : N_TOK - 1;
                gload_lds16(kh + (size_t)gk * HDIM + kc * 8, &Ks[(tid + 128 * i) * 8]);
            }
        }
#pragma unroll
        for (int i = 0; i < 8; i++)
            gload_lds16(vsrc + (size_t)(16 * i) * VT_STRIDE + kbeg, &Vs[(tid + 128 * i) * 8]);
    }

    for (int t = 0; t < ntile; t++) {
        const int kb0 = kbeg + t * 64;
        const bool fullt = (kb0 + 64 <= kend);   // false only on last tile of z=1
        const bool has_next = (t + 1 < ntile);

        // ---- K(t) ready: drain all but the 8 newest (V(t)); cross-wave barrier
        asm volatile("s_waitcnt vmcnt(8)" ::: "memory");
        __builtin_amdgcn_sched_barrier(0);
        __builtin_amdgcn_s_barrier();

        // ---- S^T = K Q^T for both sets; K-frags read ONCE, used TWICE
        floatx4 sa0[4] = {}, sa1[4] = {};
        __builtin_amdgcn_s_setprio(1);
#pragma unroll
        for (int j = 0; j < 4; j++) {
            bf16x8 bkf[4];
#pragma unroll
            for (int ks = 0; ks < 4; ks++)
                bkf[ks] = *(const bf16x8*)&Ks[(j * 16 + l16) * HDIM + koff[ks]];
#pragma unroll
            for (int ks = 0; ks < 4; ks++) sa0[j] = MFMA(bkf[ks], aq0[ks], sa0[j]);
#pragma unroll
            for (int ks = 0; ks < 4; ks++) sa1[j] = MFMA(bkf[ks], aq1[ks], sa1[j]);
        }
        __builtin_amdgcn_s_setprio(0);
        __builtin_amdgcn_s_barrier();            // all waves done reading Ks

        // ---- issue K(t+1) into Ks (lands while we do softmax+PV+next wait)
        if (has_next) {
            const int kn = kb0 + 64;
            if (kn + 64 <= kend) {
#pragma unroll
                for (int i = 0; i < 8; i++)
                    gload_lds16(ksrc + (size_t)(kn + 8 * i) * HDIM, &Ks[(tid + 128 * i) * 8]);
            } else {
#pragma unroll
                for (int i = 0; i < 8; i++) {
                    int gk = kn + krow0 + 8 * i;
                    gk = gk < N_TOK ? gk : N_TOK - 1;
                    gload_lds16(kh + (size_t)gk * HDIM + kc * 8, &Ks[(tid + 128 * i) * 8]);
                }
            }
        }

        // ---- per-lane tile max (own q-row slice), 2 quad shuffles, both sets
        float mt0, mt1;
        if (fullt) {
            mt0 = fmaxf(fmaxf(fmaxf(fmaxf(sa0[0][0], sa0[0][1]), fmaxf(sa0[0][2], sa0[0][3])),
                              fmaxf(fmaxf(sa0[1][0], sa0[1][1]), fmaxf(sa0[1][2], sa0[1][3]))),
                        fmaxf(fmaxf(fmaxf(sa0[2][0], sa0[2][1]), fmaxf(sa0[2][2], sa0[2][3])),
                              fmaxf(fmaxf(sa0[3][0], sa0[3][1]), fmaxf(sa0[3][2], sa0[3][3]))));
            mt1 = fmaxf(fmaxf(fmaxf(fmaxf(sa1[0][0], sa1[0][1]), fmaxf(sa1[0][2], sa1[0][3])),
                              fmaxf(fmaxf(sa1[1][0], sa1[1][1]), fmaxf(sa1[1][2], sa1[1][3]))),
                        fmaxf(fmaxf(fmaxf(sa1[2][0], sa1[2][1]), fmaxf(sa1[2][2], sa1[2][3])),
                              fmaxf(fmaxf(sa1[3][0], sa1[3][1]), fmaxf(sa1[3][2], sa1[3][3]))));
        } else {
            mt0 = -1e30f; mt1 = -1e30f;
            const int kq = kb0 + quad * 4;
#pragma unroll
            for (int j = 0; j < 4; j++)
#pragma unroll
                for (int r = 0; r < 4; r++) {
                    bool v = (kq + j * 16 + r) < kend;
                    mt0 = fmaxf(mt0, v ? sa0[j][r] : -1e30f);
                    mt1 = fmaxf(mt1, v ? sa1[j][r] : -1e30f);
                }
        }
        mt0 = fmaxf(mt0, __shfl_xor(mt0, 16));
        mt0 = fmaxf(mt0, __shfl_xor(mt0, 32));
        mt1 = fmaxf(mt1, __shfl_xor(mt1, 16));
        mt1 = fmaxf(mt1, __shfl_xor(mt1, 32));

        // ---- defer-max (T13, THR=8 in exp2 domain), both sets together
        if (__any((mt0 > m_l0 + 8.f) || (mt1 > m_l1 + 8.f))) {
            float mn0 = fmaxf(m_l0, mt0);
            float a0 = exp2f(m_l0 - mn0);
            m_l0 = mn0; l_l0 *= a0;
            float mn1 = fmaxf(m_l1, mt1);
            float a1 = exp2f(m_l1 - mn1);
            m_l1 = mn1; l_l1 *= a1;
#pragma unroll
            for (int r = 0; r < 4; r++) {
                float ar0 = __shfl(a0, quad * 4 + r, 16);
                float ar1 = __shfl(a1, quad * 4 + r, 16);
#pragma unroll
                for (int jd = 0; jd < 8; jd++) {
                    oacc0[jd][r] *= ar0;
                    oacc1[jd][r] *= ar1;
                }
            }
        }

        // ---- P = exp2(S - m): packed bf16 -> conflict-free ds_write_b64, per set
        if (fullt) {
#pragma unroll
            for (int j = 0; j < 4; j++) {
                float p0 = exp2f(sa0[j][0] - m_l0), p1 = exp2f(sa0[j][1] - m_l0);
                float p2 = exp2f(sa0[j][2] - m_l0), p3 = exp2f(sa0[j][3] - m_l0);
                l_l0 += (p0 + p1) + (p2 + p3);
                uint2 wv;
                wv.x = (unsigned)__builtin_bit_cast(unsigned short, (__bf16)p0) |
                       ((unsigned)__builtin_bit_cast(unsigned short, (__bf16)p1) << 16);
                wv.y = (unsigned)__builtin_bit_cast(unsigned short, (__bf16)p2) |
                       ((unsigned)__builtin_bit_cast(unsigned short, (__bf16)p3) << 16);
                *(uint2*)&ps0[l16 * 64 + (((j * 2 + pwq) ^ x7) << 3) + pwh] = wv;
            }
#pragma unroll
            for (int j = 0; j < 4; j++) {
                float p0 = exp2f(sa1[j][0] - m_l1), p1 = exp2f(sa1[j][1] - m_l1);
                float p2 = exp2f(sa1[j][2] - m_l1), p3 = exp2f(sa1[j][3] - m_l1);
                l_l1 += (p0 + p1) + (p2 + p3);
                uint2 wv;
                wv.x = (unsigned)__builtin_bit_cast(unsigned short, (__bf16)p0) |
                       ((unsigned)__builtin_bit_cast(unsigned short, (__bf16)p1) << 16);
                wv.y = (unsigned)__builtin_bit_cast(unsigned short, (__bf16)p2) |
                       ((unsigned)__builtin_bit_cast(unsigned short, (__bf16)p3) << 16);
                *(uint2*)&ps1[l16 * 64 + (((j * 2 + pwq) ^ x7) << 3) + pwh] = wv;
            }
        } else {
            const int kq = kb0 + quad * 4;
#pragma unroll
            for (int j = 0; j < 4; j++) {
                float p[4], q[4];
#pragma unroll
                for (int r = 0; r < 4; r++) {
                    bool v = (kq + j * 16 + r) < kend;
                    p[r] = v ? exp2f(sa0[j][r] - m_l0) : 0.f;
                    q[r] = v ? exp2f(sa1[j][r] - m_l1) : 0.f;
                    l_l0 += p[r];
                    l_l1 += q[r];
                }
                uint2 wv;
                wv.x = (unsigned)__builtin_bit_cast(unsigned short, (__bf16)p[0]) |
                       ((unsigned)__builtin_bit_cast(unsigned short, (__bf16)p[1]) << 16);
                wv.y = (unsigned)__builtin_bit_cast(unsigned short, (__bf16)p[2]) |
                       ((unsigned)__builtin_bit_cast(unsigned short, (__bf16)p[3]) << 16);
                *(uint2*)&ps0[l16 * 64 + (((j * 2 + pwq) ^ x7) << 3) + pwh] = wv;
                wv.x = (unsigned)__builtin_bit_cast(unsigned short, (__bf16)q[0]) |
                       ((unsigned)__builtin_bit_cast(unsigned short, (__bf16)q[1]) << 16);
                wv.y = (unsigned)__builtin_bit_cast(unsigned short, (__bf16)q[2]) |
                       ((unsigned)__builtin_bit_cast(unsigned short, (__bf16)q[3]) << 16);
                *(uint2*)&ps1[l16 * 64 + (((j * 2 + pwq) ^ x7) << 3) + pwh] = wv;
            }
        }

        // ---- V(t) ready: drain all but K(t+1) (8 if issued, else 0); barrier
        if (has_next) { asm volatile("s_waitcnt vmcnt(8)" ::: "memory"); }
        else          { asm volatile("s_waitcnt vmcnt(0)" ::: "memory"); }
        __builtin_amdgcn_sched_barrier(0);
        __builtin_amdgcn_s_barrier();

        // ---- O += P V; V-frags read ONCE, used TWICE
        __builtin_amdgcn_s_setprio(1);
#pragma unroll
        for (int ks = 0; ks < 2; ks++) {
            bf16x8 ap0 = *(const bf16x8*)&ps0[l16 * 64 + koff[ks]];
            bf16x8 ap1 = *(const bf16x8*)&ps1[l16 * 64 + koff[ks]];
#pragma unroll
            for (int jd = 0; jd < 8; jd++) {
                bf16x8 bvf = *(const bf16x8*)&Vs[(jd * 16 + l16) * 64 + koff[ks]];
                oacc0[jd] = MFMA(ap0, bvf, oacc0[jd]);
                oacc1[jd] = MFMA(ap1, bvf, oacc1[jd]);
            }
        }
        __builtin_amdgcn_s_setprio(0);
        __builtin_amdgcn_s_barrier();            // all waves done reading Vs

        // ---- issue V(t+1) (lands while next tile does QK+softmax)
        if (has_next) {
            const int kn = kb0 + 64;
#pragma unroll
            for (int i = 0; i < 8; i++)
                gload_lds16(vsrc + (size_t)(16 * i) * VT_STRIDE + kn, &Vs[(tid + 128 * i) * 8]);
        }
    }

    // ---- reduce l partials across quads (lanes sharing l16)
    l_l0 += __shfl_xor(l_l0, 16);
    l_l0 += __shfl_xor(l_l0, 32);
    l_l1 += __shfl_xor(l_l1, 16);
    l_l1 += __shfl_xor(l_l1, 32);

    // ---- store un-normalized O + (m,l), both sets
#pragma unroll
    for (int r = 0; r < 4; r++) {
        int rg0 = q0w + quad * 4 + r;
        if (rg0 < N_TOK) {
            size_t rbase = ((size_t)(z * NHEAD + head) * N_TOK + rg0) * HDIM;
#pragma unroll
            for (int jd = 0; jd < 8; jd++)
                Opart[rbase + jd * 16 + l16] = oacc0[jd][r];
        }
        int rg1 = q0w + 16 + quad * 4 + r;
        if (rg1 < N_TOK) {
            size_t rbase = ((size_t)(z * NHEAD + head) * N_TOK + rg1) * HDIM;
#pragma unroll
            for (int jd = 0; jd < 8; jd++)
                Opart[rbase + jd * 16 + l16] = oacc1[jd][r];
        }
    }
    if (quad == 0) {
        int rg0 = q0w + l16;
        if (rg0 < N_TOK) {
            int mi = (z * NHEAD + head) * N_TOK + rg0;
            mbuf[mi] = m_l0;
            lbuf[mi] = l_l0;
        }
        int rg1 = q0w + 16 + l16;
        if (rg1 < N_TOK) {
            int mi = (z * NHEAD + head) * N_TOK + rg1;
            mbuf[mi] = m_l1;
            lbuf[mi] = l_l1;
        }
    }
}

// ----------------------------------------------- combine the two KV splits
__global__ __launch_bounds__(256) void k_combine(const float* __restrict__ Opart,
                                                 const float* __restrict__ mbuf,
                                                 const float* __restrict__ lbuf,
                                                 unsigned short* __restrict__ ab) {
    const int R = NHEAD * N_TOK;
    int r = blockIdx.x * 8 + (threadIdx.x >> 5);
    if (r >= R) return;
    int l32 = threadIdx.x & 31;
    float m0 = mbuf[r], m1 = mbuf[R + r];
    float l0 = lbuf[r], l1 = lbuf[R + r];
    float m = fmaxf(m0, m1);
    float w0 = exp2f(m0 - m), w1 = exp2f(m1 - m);
    float inv = 1.f / (l0 * w0 + l1 * w1);
    w0 *= inv; w1 *= inv;
    float4 a = *(const float4*)&Opart[(size_t)r * HDIM + l32 * 4];
    float4 b = *(const float4*)&Opart[((size_t)R + r) * HDIM + l32 * 4];
    int head = r / N_TOK, tok = r % N_TOK;
    unsigned short* o = ab + (size_t)tok * DMODEL + head * HDIM + l32 * 4;
    uint2 pk;
    pk.x = (unsigned)f2bf(a.x * w0 + b.x * w1) | ((unsigned)f2bf(a.y * w0 + b.y * w1) << 16);
    pk.y = (unsigned)f2bf(a.z * w0 + b.z * w1) | ((unsigned)f2bf(a.w * w0 + b.w * w1) << 16);
    *(uint2*)o = pk;
}

// ---------------------------------------------------------------------------
extern "C" void kernel_launch(void* const* d_in, const int* in_sizes, int n_in,
                              void* d_out, int out_size, void* d_ws, size_t ws_size,
                              hipStream_t stream) {
    const float* x   = (const float*)d_in[0];
    const float* Wq  = (const float*)d_in[1];
    const float* bq  = (const float*)d_in[2];
    const float* Wk  = (const float*)d_in[3];
    const float* bk  = (const float*)d_in[4];
    const float* Wv  = (const float*)d_in[5];
    const float* bv  = (const float*)d_in[6];
    const float* Wo  = (const float*)d_in[7];
    const float* bo  = (const float*)d_in[8];
    const float* qsc = (const float*)d_in[9];
    const float* ksc = (const float*)d_in[10];
    const float* ft  = (const float*)d_in[11];
    const float* fh  = (const float*)d_in[12];
    const float* fw  = (const float*)d_in[13];

    // Layout note: ab sits BEFORE the fp32 region so the O-GEMM's A-tile
    // over-reads (rows 2925..2943) land inside d_ws, never past its end.
    char* ws = (char*)d_ws;
    unsigned short* xb   = (unsigned short*)ws; ws += (size_t)N_TOK * DMODEL * 2;          // 8,985,600
    unsigned short* Wt   = (unsigned short*)ws; ws += (size_t)4 * DMODEL * DMODEL * 2;     // 18,874,368
    unsigned short* ab   = (unsigned short*)ws; ws += (size_t)N_TOK * DMODEL * 2;          // 8,985,600
    char* qkvf_region    = ws;                  ws += (size_t)3 * N_TOK * DMODEL * 4;      // 53,913,600
    unsigned short* qkvb = (unsigned short*)ws; ws += (size_t)3 * N_TOK * DMODEL * 2;      // 26,956,800

    // Phase 1: qkvf_region holds fp32 QKV projections (53.9 MB).
    float* Qf = (float*)qkvf_region;
    float* Kf = Qf + (size_t)N_TOK * DMODEL;
    float* Vf = Qf + (size_t)2 * N_TOK * DMODEL;
    // Phase 2 (after k_norm_rope): Opart 35.9MB | m/l 0.56MB | vt 9.04MB = 45.5MB.
    float* Opart = (float*)qkvf_region;
    float* mbuf  = Opart + (size_t)2 * NHEAD * N_TOK * HDIM;
    float* lbuf  = mbuf + (size_t)2 * NHEAD * N_TOK;
    unsigned short* vtp = (unsigned short*)(lbuf + (size_t)2 * NHEAD * N_TOK);

    unsigned short* qbp = qkvb;
    unsigned short* kbp = qkvb + (size_t)N_TOK * DMODEL;
    unsigned short* vbp = qkvb + (size_t)2 * N_TOK * DMODEL;

    const int nelem = N_TOK * DMODEL;
    k_convert_x<<<(nelem / 4 + 255) / 256, 256, 0, stream>>>(x, xb, nelem);
    k_transpose_w<<<dim3(48, 48, 4), dim3(32, 8), 0, stream>>>(Wq, Wk, Wv, Wo, Wt);
    k_gemm<<<dim3(12, 23, 3), 256, 0, stream>>>(xb, Wt, bq, bk, bv, Qf, N_TOK);
    k_norm_rope<<<N_TOK, 256, 0, stream>>>(Qf, Kf, Vf, qsc, ksc, ft, fh, fw, qbp, kbp, vbp);
    k_transpose_v<<<dim3(92, 4, NHEAD), dim3(32, 8), 0, stream>>>(vbp, vtp);
    k_attn_part<<<dim3(46, NHEAD, 2), 128, 0, stream>>>(qbp, kbp, vtp, Opart, mbuf, lbuf);
    k_combine<<<(NHEAD * N_TOK + 7) / 8, 256, 0, stream>>>(Opart, mbuf, lbuf, ab);
    k_gemm<<<dim3(12, 23, 1), 256, 0, stream>>>(ab, Wt + (size_t)3 * DMODEL * DMODEL,
                                                bo, bo, bo, (float*)d_out, N_TOK);
}

// Round 6
// 367.961 us; speedup vs baseline: 1.0707x; 1.0707x over previous
//
#include <hip/hip_runtime.h>

// ---------------------------------------------------------------------------
// MultiHeadAttention (B=1, N=2925, D_MODEL=1536, 12 heads x 128) on gfx950.
// convert/transpose -> fused QKV bf16-MFMA GEMM (global_load_lds staging,
// XCD-swizzled, 3 blocks/CU) -> RMSNorm+3D RoPE (exp2-domain q-scale) ->
// V transpose -> split-KV flash attention (swapped-QK^T, phase-shifted async
// staging, counted vmcnt, raw barriers, XCD swizzle, setprio) -> combine ->
// O GEMM.
// ---------------------------------------------------------------------------

#define N_TOK 2925
#define DMODEL 1536
#define NHEAD 12
#define HDIM 128
#define KSPLIT 1472           // split-KV boundary (23 tiles of 64)
#define VT_STRIDE 2944        // N_TOK padded to x64; pad MUST be zeroed (NaN hazard)

typedef __attribute__((ext_vector_type(8))) __bf16 bf16x8;
typedef __attribute__((ext_vector_type(4))) float floatx4;

#define MFMA(a, b, c) __builtin_amdgcn_mfma_f32_16x16x32_bf16((a), (b), (c), 0, 0, 0)

static __device__ __forceinline__ unsigned short f2bf(float f) {
    unsigned u = __builtin_bit_cast(unsigned, f);
    return (unsigned short)((u + 0x7fffu + ((u >> 16) & 1u)) >> 16);
}

// async global->LDS 16B/lane (emits global_load_lds_dwordx4).
// LDS dest MUST be wave-uniform-base + lane*16.
static __device__ __forceinline__ void gload_lds16(const unsigned short* g, unsigned short* l) {
    __builtin_amdgcn_global_load_lds((const __attribute__((address_space(1))) void*)g,
                                     (__attribute__((address_space(3))) void*)l, 16, 0, 0);
}

// ---------------------------------------------------------------- convert x
__global__ __launch_bounds__(256) void k_convert_x(const float* __restrict__ x,
                                                   unsigned short* __restrict__ xb, int n) {
    int i = (blockIdx.x * 256 + threadIdx.x) * 4;
    if (i < n) {
        float4 v = *(const float4*)(x + i);
        uint2 o;
        o.x = (unsigned)f2bf(v.x) | ((unsigned)f2bf(v.y) << 16);
        o.y = (unsigned)f2bf(v.z) | ((unsigned)f2bf(v.w) << 16);
        *(uint2*)(xb + i) = o;
    }
}

// ---------------------------------------------- transpose W [k][n] -> Wt [n][k] bf16
__global__ __launch_bounds__(256) void k_transpose_w(const float* __restrict__ W0,
                                                     const float* __restrict__ W1,
                                                     const float* __restrict__ W2,
                                                     const float* __restrict__ W3,
                                                     unsigned short* __restrict__ Wt) {
    __shared__ float tile[32][33];
    const float* W = blockIdx.z == 0 ? W0 : blockIdx.z == 1 ? W1 : blockIdx.z == 2 ? W2 : W3;
    unsigned short* out = Wt + (size_t)blockIdx.z * DMODEL * DMODEL;
    int tx = threadIdx.x, ty = threadIdx.y;           // 32 x 8
    int bx = blockIdx.x * 32, by = blockIdx.y * 32;
#pragma unroll
    for (int i = 0; i < 4; i++)
        tile[ty + 8 * i][tx] = W[(size_t)(by + ty + 8 * i) * DMODEL + bx + tx];
    __syncthreads();
#pragma unroll
    for (int i = 0; i < 4; i++)
        out[(size_t)(bx + ty + 8 * i) * DMODEL + by + tx] = f2bf(tile[tx][ty + 8 * i]);
}

// ------------------------------------------------------------ bf16 MFMA GEMM
// m97 structure: unpadded stride-32 LDS tiles staged via global_load_lds(16B).
// T1 XCD-bijective block swizzle (m204: handles nb%8 != 0) + 3 blocks/CU.
__global__ __launch_bounds__(256, 3) void k_gemm(const unsigned short* __restrict__ A,
                                                 const unsigned short* __restrict__ BtBase,
                                                 const float* __restrict__ b0,
                                                 const float* __restrict__ b1,
                                                 const float* __restrict__ b2,
                                                 float* __restrict__ Cbase, int M) {
    // XCD-bijective remap: consecutive per-XCD wgids walk n-tiles within one
    // m-row -> A-panel (393KB) + B matrix (4.7MB) become XCD-L2 resident.
    const int nbx = gridDim.x, nxy = gridDim.x * gridDim.y;
    const int nb = nxy * gridDim.z;
    {
    }
    const int blin = blockIdx.x + nbx * (blockIdx.y + gridDim.y * blockIdx.z);
    const int q8 = nb >> 3, r8 = nb & 7, xcd = blin & 7, idx = blin >> 3;
    const int wg = (xcd < r8) ? xcd * (q8 + 1) + idx
                              : r8 * (q8 + 1) + (xcd - r8) * q8 + idx;
    const int z = wg / nxy;
    const int rem = wg % nxy;
    const int bym = rem / nbx, bxn = rem % nbx;

    const unsigned short* Bt = BtBase + (size_t)z * DMODEL * DMODEL;
    const float* bias = (z == 0) ? b0 : (z == 1) ? b1 : b2;
    float* C = Cbase + (size_t)z * M * DMODEL;

    __shared__ __align__(16) unsigned short As[128 * 32];   // [row][k], contiguous
    __shared__ __align__(16) unsigned short Bs[128 * 32];   // [n][k],   contiguous

    const int tid = threadIdx.x;
    const int wave = tid >> 6, lane = tid & 63, quad = lane >> 4, l16 = lane & 15;
    const int wr = wave >> 1, wc = wave & 1;
    const int m0 = bym * 128, n0 = bxn * 128;

    // staging coords: thread covers row r4 (+64 on 2nd issue), 16B col chunk c4
    const int r4 = tid >> 2, c4 = (tid & 3) * 8;
    // NOTE: A rows m0+r4(+64) may exceed M (max 2943 > 2924): reads land in the
    // next ws region (no fault); garbage only reaches acc rows discarded by rg<M.

    floatx4 acc[4][4] = {};

    for (int k0 = 0; k0 < DMODEL; k0 += 32) {
        gload_lds16(A + (size_t)(m0 + r4) * DMODEL + k0 + c4,       &As[r4 * 32 + c4]);
        gload_lds16(A + (size_t)(m0 + r4 + 64) * DMODEL + k0 + c4,  &As[(r4 + 64) * 32 + c4]);
        gload_lds16(Bt + (size_t)(n0 + r4) * DMODEL + k0 + c4,      &Bs[r4 * 32 + c4]);
        gload_lds16(Bt + (size_t)(n0 + r4 + 64) * DMODEL + k0 + c4, &Bs[(r4 + 64) * 32 + c4]);
        __syncthreads();

        bf16x8 af[4], bfm[4];
#pragma unroll
        for (int i = 0; i < 4; i++)
            af[i] = *(const bf16x8*)&As[(wr * 64 + i * 16 + l16) * 32 + quad * 8];
#pragma unroll
        for (int j = 0; j < 4; j++)
            bfm[j] = *(const bf16x8*)&Bs[(wc * 64 + j * 16 + l16) * 32 + quad * 8];
#pragma unroll
        for (int i = 0; i < 4; i++)
#pragma unroll
            for (int j = 0; j < 4; j++)
                acc[i][j] = MFMA(af[i], bfm[j], acc[i][j]);
        __syncthreads();
    }

#pragma unroll
    for (int j = 0; j < 4; j++) {
        int cg = n0 + wc * 64 + j * 16 + l16;
        float bv = bias[cg];
#pragma unroll
        for (int i = 0; i < 4; i++) {
            int rbase = m0 + wr * 64 + i * 16 + quad * 4;
#pragma unroll
            for (int r = 0; r < 4; r++) {
                int rg = rbase + r;
                if (rg < M) C[(size_t)rg * DMODEL + cg] = acc[i][j][r] + bv;
            }
        }
    }
}

// ---------------------------------- fused RMSNorm (full 1536) + 3D RoPE + pack
// q pre-scaled by (1/sqrt(HDIM))*log2(e) -> softmax runs in exp2 domain.
__global__ __launch_bounds__(256) void k_norm_rope(const float* __restrict__ Qf,
                                                   const float* __restrict__ Kf,
                                                   const float* __restrict__ Vf,
                                                   const float* __restrict__ qsc,
                                                   const float* __restrict__ ksc,
                                                   const float* __restrict__ ft,
                                                   const float* __restrict__ fh,
                                                   const float* __restrict__ fw,
                                                   unsigned short* __restrict__ qb,
                                                   unsigned short* __restrict__ kb,
                                                   unsigned short* __restrict__ vb) {
    const int n = blockIdx.x;
    const int tid = threadIdx.x, wave = tid >> 6, lane = tid & 63;
    const int t_i = n / 225, rem = n % 225, h_i = rem / 15, w_i = rem % 15;
    const float att_scale = 0.08838834764831845f * 1.4426950408889634f;  // 1/sqrt(128)*log2e

    float2 qv[3], kv[3], vv[3];
    float sq = 0.f, sk = 0.f;
#pragma unroll
    for (int c = 0; c < 3; c++) {
        int p = tid + 256 * c;
        qv[c] = *(const float2*)(Qf + (size_t)n * DMODEL + 2 * p);
        kv[c] = *(const float2*)(Kf + (size_t)n * DMODEL + 2 * p);
        vv[c] = *(const float2*)(Vf + (size_t)n * DMODEL + 2 * p);
        sq += qv[c].x * qv[c].x + qv[c].y * qv[c].y;
        sk += kv[c].x * kv[c].x + kv[c].y * kv[c].y;
    }
#pragma unroll
    for (int off = 32; off >= 1; off >>= 1) {
        sq += __shfl_xor(sq, off, 64);
        sk += __shfl_xor(sk, off, 64);
    }
    __shared__ float red[2][4];
    if (lane == 0) { red[0][wave] = sq; red[1][wave] = sk; }
    __syncthreads();
    sq = red[0][0] + red[0][1] + red[0][2] + red[0][3];
    sk = red[1][0] + red[1][1] + red[1][2] + red[1][3];
    const float rq = rsqrtf(sq * (1.f / 1536.f) + 1e-6f) * att_scale;
    const float rk = rsqrtf(sk * (1.f / 1536.f) + 1e-6f);

#pragma unroll
    for (int c = 0; c < 3; c++) {
        int p = tid + 256 * c;
        int hd = p >> 6, pl = p & 63, dd = 2 * pl;
        float cs, sn;
        if (pl < 22)      { cs = ft[t_i * 44 + 2 * pl];        sn = ft[t_i * 44 + 2 * pl + 1]; }
        else if (pl < 43) { int pp = pl - 22; cs = fh[h_i * 42 + 2 * pp]; sn = fh[h_i * 42 + 2 * pp + 1]; }
        else              { int pp = pl - 43; cs = fw[w_i * 42 + 2 * pp]; sn = fw[w_i * 42 + 2 * pp + 1]; }
        int hidx = hd * 128 + dd;
        float q0 = qv[c].x * rq * qsc[hidx], q1 = qv[c].y * rq * qsc[hidx + 1];
        float k0 = kv[c].x * rk * ksc[hidx], k1 = kv[c].y * rk * ksc[hidx + 1];
        size_t o = ((size_t)hd * N_TOK + n) * HDIM + dd;
        unsigned qo = (unsigned)f2bf(q0 * cs - q1 * sn) | ((unsigned)f2bf(q0 * sn + q1 * cs) << 16);
        unsigned ko = (unsigned)f2bf(k0 * cs - k1 * sn) | ((unsigned)f2bf(k0 * sn + k1 * cs) << 16);
        unsigned vo = (unsigned)f2bf(vv[c].x) | ((unsigned)f2bf(vv[c].y) << 16);
        *(unsigned*)(qb + o) = qo;
        *(unsigned*)(kb + o) = ko;
        *(unsigned*)(vb + o) = vo;
    }
}

// ----------------- transpose V: [head][tok][128] -> [head][128][VT_STRIDE] bf16
// Pad columns [N_TOK, VT_STRIDE) are WRITTEN AS ZERO (recycled region NaN hazard).
__global__ __launch_bounds__(256) void k_transpose_v(const unsigned short* __restrict__ vbi,
                                                     unsigned short* __restrict__ vt) {
    __shared__ unsigned short tile[32][33];
    const int head = blockIdx.z;
    const int t0 = blockIdx.x * 32, d0 = blockIdx.y * 32;
    const int tx = threadIdx.x, ty = threadIdx.y;      // 32 x 8
#pragma unroll
    for (int i = 0; i < 4; i++) {
        int t = t0 + ty + 8 * i;
        tile[ty + 8 * i][tx] = (t < N_TOK) ? vbi[((size_t)head * N_TOK + t) * HDIM + d0 + tx] : 0;
    }
    __syncthreads();
    int t = t0 + tx;                                   // < VT_STRIDE always
#pragma unroll
    for (int i = 0; i < 4; i++)
        vt[((size_t)head * HDIM + d0 + ty + 8 * i) * VT_STRIDE + t] = tile[tx][ty + 8 * i];
}

// ------------- split-KV flash attention, phase-shifted async pipeline (R7)
// Block = (q-tile 64 rows, head, split). 4 waves x 16 rows each. KV tiles of 64.
// exp2-domain softmax (log2e folded into q).  Swapped QK^T: sa[j][r] =
// S[qrow=l16][key=j*16+quad*4+r] -> lane-local softmax, b64 P writes.
//
// Pipeline (T3/T4-lite, NO extra LDS -> stays 4 blocks/CU):
//   top:   vmcnt(4) [drain K(t), V(t) in flight] ; barrier ; QK
//   post-QK barrier ; issue K(t+1)  (hidden under softmax+PV+next-QK)
//   pre-PV: vmcnt(4) [drain V(t), K(t+1) in flight] ; barrier ; PV
//   post-PV barrier ; issue V(t+1)  (hidden under next QK+softmax)
// All barriers are raw s_barrier (no compiler vmcnt(0) drain).  Each wave
// waits its OWN vmcnt then barriers => cross-wave staging visibility.
// Q global loads are oldest in the FIFO -> drained by the first vmcnt(4).
// XCD swizzle: 1104 blocks = 8 x 138; each XCD gets 3 heads' contiguous
// q-blocks (K/V slice ~2.3MB fits 4MB XCD L2).
// LDS total = 16384 (K) + 16384 (V^T) + 8192 (P) = 40960 -> 4 blocks/CU.
__global__ __launch_bounds__(256, 4) void k_attn_part(const unsigned short* __restrict__ qb,
                                                      const unsigned short* __restrict__ kb,
                                                      const unsigned short* __restrict__ vt,
                                                      float* __restrict__ Opart,
                                                      float* __restrict__ mbuf,
                                                      float* __restrict__ lbuf) {
    __shared__ __align__(16) unsigned short Ks[64 * 128];   // [key][d]   linear+swz
    __shared__ __align__(16) unsigned short Vs[128 * 64];   // [d][key]   linear+swz
    __shared__ __align__(16) unsigned short Ps[4][16 * 64]; // per-wave P [qrow][key] swz

    // XCD-aware remap (bijective: 1104 = 8*138)
    const int b = blockIdx.x + 46 * (blockIdx.y + 12 * (int)blockIdx.z);
    const int w = (b & 7) * 138 + (b >> 3);
    const int qblk = w % 46;
    const int head = (w / 46) % 12;
    const int z    = w / 552;

    const int tid = threadIdx.x, wave = tid >> 6, lane = tid & 63;
    const int quad = lane >> 4, l16 = lane & 15, x7 = l16 & 7;
    const int q0 = qblk * 64 + wave * 16;
    const unsigned short* qh = qb + (size_t)head * N_TOK * HDIM;
    const unsigned short* kh = kb + (size_t)head * N_TOK * HDIM;
    const unsigned short* vh = vt + (size_t)head * HDIM * VT_STRIDE;
    unsigned short* ps = Ps[wave];

    const int kbeg = z ? KSPLIT : 0;
    const int kend = z ? N_TOK : KSPLIT;
    const int ntile = (kend - kbeg + 63) >> 6;

    // swizzled 16B-chunk read offsets (in shorts); chunk c = ks*4+quad, row&7 = l16&7.
    int koff[4];
#pragma unroll
    for (int ks = 0; ks < 4; ks++) {
        int c = ks * 4 + quad;
        koff[ks] = ((c & 8) | ((c & 7) ^ x7)) * 8;
    }
    // P write base: row l16, chunk (j*2 + (quad>>1)) ^ x7, half (quad&1).
    const int pwq = (quad >> 1), pwh = (quad & 1) * 4;

    // staging: thread covers LDS chunk (tid + 256*i), i=0..3 (lane-linear dest).
    const int krow = tid >> 4, ksw = tid & 15;
    const int kc = (ksw & 8) | ((ksw & 7) ^ (krow & 7));   // (krow+16i)&7 == krow&7
    const int vd = tid >> 3, vsw = tid & 7;
    const int vc = vsw ^ (vd & 7);                          // (vd+32i)&7 == vd&7
    const unsigned short* ksrc = kh + (size_t)krow * HDIM + kc * 8;
    const unsigned short* vsrc = vh + (size_t)vd * VT_STRIDE + vc * 8;

    // Q fragments (loaded FIRST: oldest vmcnt entries, drained by first vmcnt(4))
    bf16x8 aq[4];
    {
        int qrow = q0 + l16;
        if (qrow < N_TOK) {
#pragma unroll
            for (int ks = 0; ks < 4; ks++)
                aq[ks] = *(const bf16x8*)&qh[(size_t)qrow * HDIM + ks * 32 + quad * 8];
        } else {
#pragma unroll
            for (int ks = 0; ks < 4; ks++) aq[ks] = (bf16x8)(__bf16)0.0f;
        }
    }

    floatx4 oacc[8] = {};
    float m_l = -1e30f;   // running max of lane's own q-row (l16)
    float l_l = 0.f;      // per-lane PARTIAL sum (reduced over quads at end)

    // ---- prologue: issue K(0) then V(0)  (4 loads each per thread-group)
    {
        const bool part0 = (kbeg + 64 > kend);
        if (!part0) {
#pragma unroll
            for (int i = 0; i < 4; i++)
                gload_lds16(ksrc + (size_t)(kbeg + 16 * i) * HDIM, &Ks[(tid + 256 * i) * 8]);
        } else {
#pragma unroll
            for (int i = 0; i < 4; i++) {
                int gk = kbeg + krow + 16 * i;
                gk = gk < N_TOK ? gk : N_TOK - 1;
                gload_lds16(kh + (size_t)gk * HDIM + kc * 8, &Ks[(tid + 256 * i) * 8]);
            }
        }
#pragma unroll
        for (int i = 0; i < 4; i++)
            gload_lds16(vsrc + (size_t)(32 * i) * VT_STRIDE + kbeg, &Vs[(tid + 256 * i) * 8]);
    }

    for (int t = 0; t < ntile; t++) {
        const int kb0 = kbeg + t * 64;
        const bool fullt = (kb0 + 64 <= kend);   // false only on last tile of z=1
        const bool has_next = (t + 1 < ntile);

        // ---- K(t) ready: drain all but the 4 newest (V(t)); cross-wave barrier
        asm volatile("s_waitcnt vmcnt(4)" ::: "memory");
        __builtin_amdgcn_sched_barrier(0);
        __builtin_amdgcn_s_barrier();

        // ---- S^T = K Q^T : sa[j][r] = S[l16][kb0 + j*16 + quad*4 + r]
        floatx4 sa[4] = {};
        __builtin_amdgcn_s_setprio(1);
#pragma unroll
        for (int j = 0; j < 4; j++)
#pragma unroll
            for (int ks = 0; ks < 4; ks++) {
                bf16x8 bkf = *(const bf16x8*)&Ks[(j * 16 + l16) * HDIM + koff[ks]];
                sa[j] = MFMA(bkf, aq[ks], sa[j]);
            }
        __builtin_amdgcn_s_setprio(0);
        __builtin_amdgcn_s_barrier();            // all waves done reading Ks

        // ---- issue K(t+1) into Ks (lands while we do softmax+PV+next wait)
        if (has_next) {
            const int kn = kb0 + 64;
            if (kn + 64 <= kend) {
#pragma unroll
                for (int i = 0; i < 4; i++)
                    gload_lds16(ksrc + (size_t)(kn + 16 * i) * HDIM, &Ks[(tid + 256 * i) * 8]);
            } else {
#pragma unroll
                for (int i = 0; i < 4; i++) {
                    int gk = kn + krow + 16 * i;
                    gk = gk < N_TOK ? gk : N_TOK - 1;
                    gload_lds16(kh + (size_t)gk * HDIM + kc * 8, &Ks[(tid + 256 * i) * 8]);
                }
            }
        }

        // ---- per-lane tile max over its 16 S values, 2 quad shuffles
        float mt;
        if (fullt) {
            float m01 = fmaxf(fmaxf(sa[0][0], sa[0][1]), fmaxf(sa[0][2], sa[0][3]));
            float m23 = fmaxf(fmaxf(sa[1][0], sa[1][1]), fmaxf(sa[1][2], sa[1][3]));
            float m45 = fmaxf(fmaxf(sa[2][0], sa[2][1]), fmaxf(sa[2][2], sa[2][3]));
            float m67 = fmaxf(fmaxf(sa[3][0], sa[3][1]), fmaxf(sa[3][2], sa[3][3]));
            mt = fmaxf(fmaxf(m01, m23), fmaxf(m45, m67));
        } else {
            mt = -1e30f;
            const int kq = kb0 + quad * 4;
#pragma unroll
            for (int j = 0; j < 4; j++)
#pragma unroll
                for (int r = 0; r < 4; r++)
                    mt = fmaxf(mt, (kq + j * 16 + r < kend) ? sa[j][r] : -1e30f);
        }
        mt = fmaxf(mt, __shfl_xor(mt, 16));
        mt = fmaxf(mt, __shfl_xor(mt, 32));

        // ---- defer-max (T13, THR=8 in exp2 domain)
        if (__any(mt > m_l + 8.f)) {
            float mn = fmaxf(m_l, mt);
            float alpha = exp2f(m_l - mn);
            m_l = mn;
            l_l *= alpha;
#pragma unroll
            for (int r = 0; r < 4; r++) {
                float ar = __shfl(alpha, quad * 4 + r, 16);
#pragma unroll
                for (int jd = 0; jd < 8; jd++) oacc[jd][r] *= ar;
            }
        }

        // ---- P = exp2(S - m): 4 keys/lane/j, packed bf16 -> ds_write_b64
        if (fullt) {
#pragma unroll
            for (int j = 0; j < 4; j++) {
                float p0 = exp2f(sa[j][0] - m_l), p1 = exp2f(sa[j][1] - m_l);
                float p2 = exp2f(sa[j][2] - m_l), p3 = exp2f(sa[j][3] - m_l);
                l_l += (p0 + p1) + (p2 + p3);
                uint2 wv;
                wv.x = (unsigned)__builtin_bit_cast(unsigned short, (__bf16)p0) |
                       ((unsigned)__builtin_bit_cast(unsigned short, (__bf16)p1) << 16);
                wv.y = (unsigned)__builtin_bit_cast(unsigned short, (__bf16)p2) |
                       ((unsigned)__builtin_bit_cast(unsigned short, (__bf16)p3) << 16);
                *(uint2*)&ps[l16 * 64 + (((j * 2 + pwq) ^ x7) << 3) + pwh] = wv;
            }
        } else {
            const int kq = kb0 + quad * 4;
#pragma unroll
            for (int j = 0; j < 4; j++) {
                float p[4];
#pragma unroll
                for (int r = 0; r < 4; r++) {
                    p[r] = (kq + j * 16 + r < kend) ? exp2f(sa[j][r] - m_l) : 0.f;
                    l_l += p[r];
                }
                uint2 wv;
                wv.x = (unsigned)__builtin_bit_cast(unsigned short, (__bf16)p[0]) |
                       ((unsigned)__builtin_bit_cast(unsigned short, (__bf16)p[1]) << 16);
                wv.y = (unsigned)__builtin_bit_cast(unsigned short, (__bf16)p[2]) |
                       ((unsigned)__builtin_bit_cast(unsigned short, (__bf16)p[3]) << 16);
                *(uint2*)&ps[l16 * 64 + (((j * 2 + pwq) ^ x7) << 3) + pwh] = wv;
            }
        }

        // ---- V(t) ready: drain all but K(t+1) (4 if issued, else 0); barrier
        if (has_next) { asm volatile("s_waitcnt vmcnt(4)" ::: "memory"); }
        else          { asm volatile("s_waitcnt vmcnt(0)" ::: "memory"); }
        __builtin_amdgcn_sched_barrier(0);
        __builtin_amdgcn_s_barrier();

        // ---- O += P V
        __builtin_amdgcn_s_setprio(1);
#pragma unroll
        for (int ks = 0; ks < 2; ks++) {
            bf16x8 ap = *(const bf16x8*)&ps[l16 * 64 + koff[ks]];
#pragma unroll
            for (int jd = 0; jd < 8; jd++) {
                bf16x8 bvf = *(const bf16x8*)&Vs[(jd * 16 + l16) * 64 + koff[ks]];
                oacc[jd] = MFMA(ap, bvf, oacc[jd]);
            }
        }
        __builtin_amdgcn_s_setprio(0);
        __builtin_amdgcn_s_barrier();            // all waves done reading Vs

        // ---- issue V(t+1) (lands while next tile does QK+softmax)
        if (has_next) {
            const int kn = kb0 + 64;
#pragma unroll
            for (int i = 0; i < 4; i++)
                gload_lds16(vsrc + (size_t)(32 * i) * VT_STRIDE + kn, &Vs[(tid + 256 * i) * 8]);
        }
    }

    // ---- reduce l partials across quads (lanes sharing l16)
    l_l += __shfl_xor(l_l, 16);
    l_l += __shfl_xor(l_l, 32);

    // ---- store un-normalized O + (m,l)
#pragma unroll
    for (int r = 0; r < 4; r++) {
        int rg = q0 + quad * 4 + r;
        if (rg < N_TOK) {
            size_t rbase = ((size_t)(z * NHEAD + head) * N_TOK + rg) * HDIM;
#pragma unroll
            for (int jd = 0; jd < 8; jd++)
                Opart[rbase + jd * 16 + l16] = oacc[jd][r];
        }
    }
    if (quad == 0 && q0 + l16 < N_TOK) {
        int mi = (z * NHEAD + head) * N_TOK + q0 + l16;
        mbuf[mi] = m_l;
        lbuf[mi] = l_l;
    }
}

// ----------------------------------------------- combine the two KV splits
__global__ __launch_bounds__(256) void k_combine(const float* __restrict__ Opart,
                                                 const float* __restrict__ mbuf,
                                                 const float* __restrict__ lbuf,
                                                 unsigned short* __restrict__ ab) {
    const int R = NHEAD * N_TOK;
    int r = blockIdx.x * 8 + (threadIdx.x >> 5);
    if (r >= R) return;
    int l32 = threadIdx.x & 31;
    float m0 = mbuf[r], m1 = mbuf[R + r];
    float l0 = lbuf[r], l1 = lbuf[R + r];
    float m = fmaxf(m0, m1);
    float w0 = exp2f(m0 - m), w1 = exp2f(m1 - m);
    float inv = 1.f / (l0 * w0 + l1 * w1);
    w0 *= inv; w1 *= inv;
    float4 a = *(const float4*)&Opart[(size_t)r * HDIM + l32 * 4];
    float4 b = *(const float4*)&Opart[((size_t)R + r) * HDIM + l32 * 4];
    int head = r / N_TOK, tok = r % N_TOK;
    unsigned short* o = ab + (size_t)tok * DMODEL + head * HDIM + l32 * 4;
    uint2 pk;
    pk.x = (unsigned)f2bf(a.x * w0 + b.x * w1) | ((unsigned)f2bf(a.y * w0 + b.y * w1) << 16);
    pk.y = (unsigned)f2bf(a.z * w0 + b.z * w1) | ((unsigned)f2bf(a.w * w0 + b.w * w1) << 16);
    *(uint2*)o = pk;
}

// ---------------------------------------------------------------------------
extern "C" void kernel_launch(void* const* d_in, const int* in_sizes, int n_in,
                              void* d_out, int out_size, void* d_ws, size_t ws_size,
                              hipStream_t stream) {
    const float* x   = (const float*)d_in[0];
    const float* Wq  = (const float*)d_in[1];
    const float* bq  = (const float*)d_in[2];
    const float* Wk  = (const float*)d_in[3];
    const float* bk  = (const float*)d_in[4];
    const float* Wv  = (const float*)d_in[5];
    const float* bv  = (const float*)d_in[6];
    const float* Wo  = (const float*)d_in[7];
    const float* bo  = (const float*)d_in[8];
    const float* qsc = (const float*)d_in[9];
    const float* ksc = (const float*)d_in[10];
    const float* ft  = (const float*)d_in[11];
    const float* fh  = (const float*)d_in[12];
    const float* fw  = (const float*)d_in[13];

    // Layout note: ab sits BEFORE the fp32 region so the O-GEMM's A-tile
    // over-reads (rows 2925..2943) land inside d_ws, never past its end.
    char* ws = (char*)d_ws;
    unsigned short* xb   = (unsigned short*)ws; ws += (size_t)N_TOK * DMODEL * 2;          // 8,985,600
    unsigned short* Wt   = (unsigned short*)ws; ws += (size_t)4 * DMODEL * DMODEL * 2;     // 18,874,368
    unsigned short* ab   = (unsigned short*)ws; ws += (size_t)N_TOK * DMODEL * 2;          // 8,985,600
    char* qkvf_region    = ws;                  ws += (size_t)3 * N_TOK * DMODEL * 4;      // 53,913,600
    unsigned short* qkvb = (unsigned short*)ws; ws += (size_t)3 * N_TOK * DMODEL * 2;      // 26,956,800

    // Phase 1: qkvf_region holds fp32 QKV projections (53.9 MB).
    float* Qf = (float*)qkvf_region;
    float* Kf = Qf + (size_t)N_TOK * DMODEL;
    float* Vf = Qf + (size_t)2 * N_TOK * DMODEL;
    // Phase 2 (after k_norm_rope): Opart 35.9MB | m/l 0.56MB | vt 9.04MB = 45.5MB.
    float* Opart = (float*)qkvf_region;
    float* mbuf  = Opart + (size_t)2 * NHEAD * N_TOK * HDIM;
    float* lbuf  = mbuf + (size_t)2 * NHEAD * N_TOK;
    unsigned short* vtp = (unsigned short*)(lbuf + (size_t)2 * NHEAD * N_TOK);

    unsigned short* qbp = qkvb;
    unsigned short* kbp = qkvb + (size_t)N_TOK * DMODEL;
    unsigned short* vbp = qkvb + (size_t)2 * N_TOK * DMODEL;

    const int nelem = N_TOK * DMODEL;
    k_convert_x<<<(nelem / 4 + 255) / 256, 256, 0, stream>>>(x, xb, nelem);
    k_transpose_w<<<dim3(48, 48, 4), dim3(32, 8), 0, stream>>>(Wq, Wk, Wv, Wo, Wt);
    k_gemm<<<dim3(12, 23, 3), 256, 0, stream>>>(xb, Wt, bq, bk, bv, Qf, N_TOK);
    k_norm_rope<<<N_TOK, 256, 0, stream>>>(Qf, Kf, Vf, qsc, ksc, ft, fh, fw, qbp, kbp, vbp);
    k_transpose_v<<<dim3(92, 4, NHEAD), dim3(32, 8), 0, stream>>>(vbp, vtp);
    k_attn_part<<<dim3(46, NHEAD, 2), 256, 0, stream>>>(qbp, kbp, vtp, Opart, mbuf, lbuf);
    k_combine<<<(NHEAD * N_TOK + 7) / 8, 256, 0, stream>>>(Opart, mbuf, lbuf, ab);
    k_gemm<<<dim3(12, 23, 1), 256, 0, stream>>>(ab, Wt + (size_t)3 * DMODEL * DMODEL,
                                                bo, bo, bo, (float*)d_out, N_TOK);
}

// Round 7
// 355.564 us; speedup vs baseline: 1.1080x; 1.0349x over previous
//
#include <hip/hip_runtime.h>

// ---------------------------------------------------------------------------
// MultiHeadAttention (B=1, N=2925, D_MODEL=1536, 12 heads x 128) on gfx950.
// convert/transpose -> QKV bf16 GEMM (256x256 double-buffered counted-vmcnt
// pipeline, T2 swizzle) -> RMSNorm+3D RoPE -> V transpose -> split-KV flash
// attention (swapped-QK^T, phase-shifted staging) -> combine -> O GEMM (128^2).
// ---------------------------------------------------------------------------

#define N_TOK 2925
#define DMODEL 1536
#define NHEAD 12
#define HDIM 128
#define KSPLIT 1472           // split-KV boundary (23 tiles of 64)
#define VT_STRIDE 2944        // N_TOK padded to x64; pad MUST be zeroed (NaN hazard)

typedef __attribute__((ext_vector_type(8))) __bf16 bf16x8;
typedef __attribute__((ext_vector_type(4))) float floatx4;

#define MFMA(a, b, c) __builtin_amdgcn_mfma_f32_16x16x32_bf16((a), (b), (c), 0, 0, 0)

static __device__ __forceinline__ unsigned short f2bf(float f) {
    unsigned u = __builtin_bit_cast(unsigned, f);
    return (unsigned short)((u + 0x7fffu + ((u >> 16) & 1u)) >> 16);
}

// async global->LDS 16B/lane (emits global_load_lds_dwordx4).
// LDS dest MUST be wave-uniform-base + lane*16.
static __device__ __forceinline__ void gload_lds16(const unsigned short* g, unsigned short* l) {
    __builtin_amdgcn_global_load_lds((const __attribute__((address_space(1))) void*)g,
                                     (__attribute__((address_space(3))) void*)l, 16, 0, 0);
}

// ---------------------------------------------------------------- convert x
__global__ __launch_bounds__(256) void k_convert_x(const float* __restrict__ x,
                                                   unsigned short* __restrict__ xb, int n) {
    int i = (blockIdx.x * 256 + threadIdx.x) * 4;
    if (i < n) {
        float4 v = *(const float4*)(x + i);
        uint2 o;
        o.x = (unsigned)f2bf(v.x) | ((unsigned)f2bf(v.y) << 16);
        o.y = (unsigned)f2bf(v.z) | ((unsigned)f2bf(v.w) << 16);
        *(uint2*)(xb + i) = o;
    }
}

// ---------------------------------------------- transpose W [k][n] -> Wt [n][k] bf16
__global__ __launch_bounds__(256) void k_transpose_w(const float* __restrict__ W0,
                                                     const float* __restrict__ W1,
                                                     const float* __restrict__ W2,
                                                     const float* __restrict__ W3,
                                                     unsigned short* __restrict__ Wt) {
    __shared__ float tile[32][33];
    const float* W = blockIdx.z == 0 ? W0 : blockIdx.z == 1 ? W1 : blockIdx.z == 2 ? W2 : W3;
    unsigned short* out = Wt + (size_t)blockIdx.z * DMODEL * DMODEL;
    int tx = threadIdx.x, ty = threadIdx.y;           // 32 x 8
    int bx = blockIdx.x * 32, by = blockIdx.y * 32;
#pragma unroll
    for (int i = 0; i < 4; i++)
        tile[ty + 8 * i][tx] = W[(size_t)(by + ty + 8 * i) * DMODEL + bx + tx];
    __syncthreads();
#pragma unroll
    for (int i = 0; i < 4; i++)
        out[(size_t)(bx + ty + 8 * i) * DMODEL + by + tx] = f2bf(tile[tx][ty + 8 * i]);
}

// ---------------------- QKV GEMM: 256x256 tile, BK=64, 8 waves, dbuf pipeline
// LDS 128 KiB (2 bufs x (A,B) x 256x64 bf16), XOR swizzle chunk^=(row&7) on
// both sides (stage source pre-swizzled, reads swizzled).  Per K-tile, 4
// phases; staging of tile t+1 spread 1 half-tile/phase in order
// {B-top, B-bot, A-lo, A-hi} where A halves are INTERLEAVED (half h covers
// tile rows [h*64,h*64+63] and [128+h*64,...]) so every wave's m=0..3 rows
// are in A-lo and m=4..7 in A-hi.  Counted vmcnt(2) at W1 (gates B+A-lo) and
// W2 (gates A-hi); raw s_barrier (no compiler vmcnt(0) drain).
__global__ __launch_bounds__(512, 2) void k_gemm_qkv(const unsigned short* __restrict__ A,
                                                     const unsigned short* __restrict__ BtBase,
                                                     const float* __restrict__ b0,
                                                     const float* __restrict__ b1,
                                                     const float* __restrict__ b2,
                                                     float* __restrict__ Cbase, int M) {
    __shared__ __align__(16) unsigned short As[2][256 * 64];   // 2 x 32 KiB
    __shared__ __align__(16) unsigned short Bs[2][256 * 64];   // 2 x 32 KiB

    // XCD swizzle: nb = 216 = 8*27 exact
    const int blin = blockIdx.x + 6 * (blockIdx.y + 12 * (int)blockIdx.z);
    const int wg = (blin & 7) * 27 + (blin >> 3);
    const int z = wg / 72, rem = wg % 72, mt = rem / 6, ntile = rem % 6;
    const unsigned short* Bt = BtBase + (size_t)z * DMODEL * DMODEL;
    const float* bias = (z == 0) ? b0 : (z == 1) ? b1 : b2;
    float* C = Cbase + (size_t)z * M * DMODEL;
    const int m0 = mt * 256, n0 = ntile * 256;

    const int tid = threadIdx.x;
    const int wave = tid >> 6, lane = tid & 63, quad = lane >> 4, l16 = lane & 15;
    const int x7 = l16 & 7;
    const int wm = wave >> 2, wn = wave & 3;

    // swizzled read chunk offsets (shorts) for k-slice s: chunk (s*4+quad)^x7
    const int koff0 = ((quad) ^ x7) * 8;
    const int koff1 = ((4 + quad) ^ x7) * 8;

    // staging coords: thread covers chunks d = tid + 512*i (i=0,1) of a
    // 128-row half-tile; A halves interleaved, B halves plain.
    //   r7 = d>>3 (0..127), sl = tid&7, srcchunk = sl ^ (row&7)
    const int sl = tid & 7;

    floatx4 acc[8][4] = {};

    const unsigned short* Abase = A + (size_t)m0 * DMODEL;
    const unsigned short* Bbase = Bt + (size_t)n0 * DMODEL;

    // ---- half-tile stagers (2 gloads each). kt = K-tile index, buf = dest.
    auto stageB = [&](int buf, int h, int kt) {
#pragma unroll
        for (int i = 0; i < 2; i++) {
            int d = tid + 512 * i;
            int row = h * 128 + (d >> 3);                       // plain half
            int c = sl ^ (row & 7);
            gload_lds16(Bbase + (size_t)row * DMODEL + kt * 64 + c * 8,
                        &Bs[buf][(row * 8 + sl) * 8]);
        }
    };
    auto stageA = [&](int buf, int h, int kt) {
#pragma unroll
        for (int i = 0; i < 2; i++) {
            int d = tid + 512 * i;
            int r7 = d >> 3;                                    // 0..127
            int row = (r7 & 63) + h * 64 + (r7 >> 6) * 128;     // interleaved half
            int c = sl ^ (row & 7);
            gload_lds16(Abase + (size_t)row * DMODEL + kt * 64 + c * 8,
                        &As[buf][(row * 8 + sl) * 8]);
        }
    };

    // ---- prologue: stage tile 0 into buf 0 (8 loads: Btop,Bbot,Alo,Ahi)
    stageB(0, 0, 0); stageB(0, 1, 0); stageA(0, 0, 0); stageA(0, 1, 0);

    const int NT = DMODEL / 64;                                  // 24
    for (int t = 0; t < NT; t++) {
        const int c = t & 1, sb = c ^ 1;
        const int ts = (t + 1 < NT) ? t + 1 : NT - 1;            // clamped (uniform ledger)

        // ---- W1: B(both)+A-lo of tile t visible (leaves A-hi in flight)
        asm volatile("s_waitcnt vmcnt(2)" ::: "memory");
        __builtin_amdgcn_sched_barrier(0);
        __builtin_amdgcn_s_barrier();

        // ---- P1: A m=0..3 s0 + B s0 ; stage B-top(ts) ; MFMA h0s0
        bf16x8 af[4], bfm[4];
#pragma unroll
        for (int m = 0; m < 4; m++)
            af[m] = *(const bf16x8*)&As[c][(wm * 128 + m * 16 + l16) * 64 + koff0];
#pragma unroll
        for (int n = 0; n < 4; n++)
            bfm[n] = *(const bf16x8*)&Bs[c][(wn * 64 + n * 16 + l16) * 64 + koff0];
        stageB(sb, 0, ts);
        __builtin_amdgcn_s_barrier();
        __builtin_amdgcn_s_setprio(1);
#pragma unroll
        for (int m = 0; m < 4; m++)
#pragma unroll
            for (int n = 0; n < 4; n++)
                acc[m][n] = MFMA(af[m], bfm[n], acc[m][n]);
        __builtin_amdgcn_s_setprio(0);
        __builtin_amdgcn_sched_barrier(0);

        // ---- W2: A-hi of tile t visible (outstanding: A-hi(t)+Btop(ts))
        asm volatile("s_waitcnt vmcnt(2)" ::: "memory");
        __builtin_amdgcn_sched_barrier(0);
        __builtin_amdgcn_s_barrier();

        // ---- P2: A m=4..7 s0 ; stage B-bot(ts) ; MFMA h1s0
        bf16x8 af2[4];
#pragma unroll
        for (int m = 0; m < 4; m++)
            af2[m] = *(const bf16x8*)&As[c][(wm * 128 + 64 + m * 16 + l16) * 64 + koff0];
        stageB(sb, 1, ts);
        __builtin_amdgcn_s_barrier();
        __builtin_amdgcn_s_setprio(1);
#pragma unroll
        for (int m = 0; m < 4; m++)
#pragma unroll
            for (int n = 0; n < 4; n++)
                acc[4 + m][n] = MFMA(af2[m], bfm[n], acc[4 + m][n]);
        __builtin_amdgcn_s_setprio(0);
        __builtin_amdgcn_sched_barrier(0);

        // ---- P3: A m=0..3 s1 + B s1 ; stage A-lo(ts) ; MFMA h0s1 (no gate:
        //      data resident since W1/W2; stage target sb unread this tile)
#pragma unroll
        for (int m = 0; m < 4; m++)
            af[m] = *(const bf16x8*)&As[c][(wm * 128 + m * 16 + l16) * 64 + koff1];
#pragma unroll
        for (int n = 0; n < 4; n++)
            bfm[n] = *(const bf16x8*)&Bs[c][(wn * 64 + n * 16 + l16) * 64 + koff1];
        stageA(sb, 0, ts);
        __builtin_amdgcn_s_barrier();
        __builtin_amdgcn_s_setprio(1);
#pragma unroll
        for (int m = 0; m < 4; m++)
#pragma unroll
            for (int n = 0; n < 4; n++)
                acc[m][n] = MFMA(af[m], bfm[n], acc[m][n]);
        __builtin_amdgcn_s_setprio(0);
        __builtin_amdgcn_sched_barrier(0);

        // ---- P4: A m=4..7 s1 ; stage A-hi(ts) ; MFMA h1s1
#pragma unroll
        for (int m = 0; m < 4; m++)
            af2[m] = *(const bf16x8*)&As[c][(wm * 128 + 64 + m * 16 + l16) * 64 + koff1];
        stageA(sb, 1, ts);
        __builtin_amdgcn_s_barrier();
        __builtin_amdgcn_s_setprio(1);
#pragma unroll
        for (int m = 0; m < 4; m++)
#pragma unroll
            for (int n = 0; n < 4; n++)
                acc[4 + m][n] = MFMA(af2[m], bfm[n], acc[4 + m][n]);
        __builtin_amdgcn_s_setprio(0);
        __builtin_amdgcn_sched_barrier(0);
    }

    // ---- epilogue: C += bias, guarded rows
#pragma unroll
    for (int n = 0; n < 4; n++) {
        int cg = n0 + wn * 64 + n * 16 + l16;
        float bv = bias[cg];
#pragma unroll
        for (int m = 0; m < 8; m++) {
            int rbase = m0 + wm * 128 + m * 16 + quad * 4;
#pragma unroll
            for (int r = 0; r < 4; r++) {
                int rg = rbase + r;
                if (rg < M) C[(size_t)rg * DMODEL + cg] = acc[m][n][r] + bv;
            }
        }
    }
}

// ------------------------------------------------------------ bf16 MFMA GEMM
// m97 structure (used for the O projection): unpadded stride-32 LDS tiles.
__global__ __launch_bounds__(256, 3) void k_gemm(const unsigned short* __restrict__ A,
                                                 const unsigned short* __restrict__ BtBase,
                                                 const float* __restrict__ b0,
                                                 const float* __restrict__ b1,
                                                 const float* __restrict__ b2,
                                                 float* __restrict__ Cbase, int M) {
    const int nbx = gridDim.x, nxy = gridDim.x * gridDim.y;
    const int nb = nxy * gridDim.z;
    const int blin = blockIdx.x + nbx * (blockIdx.y + gridDim.y * blockIdx.z);
    const int q8 = nb >> 3, r8 = nb & 7, xcd = blin & 7, idx = blin >> 3;
    const int wg = (xcd < r8) ? xcd * (q8 + 1) + idx
                              : r8 * (q8 + 1) + (xcd - r8) * q8 + idx;
    const int z = wg / nxy;
    const int rem = wg % nxy;
    const int bym = rem / nbx, bxn = rem % nbx;

    const unsigned short* Bt = BtBase + (size_t)z * DMODEL * DMODEL;
    const float* bias = (z == 0) ? b0 : (z == 1) ? b1 : b2;
    float* C = Cbase + (size_t)z * M * DMODEL;

    __shared__ __align__(16) unsigned short As[128 * 32];
    __shared__ __align__(16) unsigned short Bs[128 * 32];

    const int tid = threadIdx.x;
    const int wave = tid >> 6, lane = tid & 63, quad = lane >> 4, l16 = lane & 15;
    const int wr = wave >> 1, wc = wave & 1;
    const int m0 = bym * 128, n0 = bxn * 128;
    const int r4 = tid >> 2, c4 = (tid & 3) * 8;

    floatx4 acc[4][4] = {};

    for (int k0 = 0; k0 < DMODEL; k0 += 32) {
        gload_lds16(A + (size_t)(m0 + r4) * DMODEL + k0 + c4,       &As[r4 * 32 + c4]);
        gload_lds16(A + (size_t)(m0 + r4 + 64) * DMODEL + k0 + c4,  &As[(r4 + 64) * 32 + c4]);
        gload_lds16(Bt + (size_t)(n0 + r4) * DMODEL + k0 + c4,      &Bs[r4 * 32 + c4]);
        gload_lds16(Bt + (size_t)(n0 + r4 + 64) * DMODEL + k0 + c4, &Bs[(r4 + 64) * 32 + c4]);
        __syncthreads();

        bf16x8 af[4], bfm[4];
#pragma unroll
        for (int i = 0; i < 4; i++)
            af[i] = *(const bf16x8*)&As[(wr * 64 + i * 16 + l16) * 32 + quad * 8];
#pragma unroll
        for (int j = 0; j < 4; j++)
            bfm[j] = *(const bf16x8*)&Bs[(wc * 64 + j * 16 + l16) * 32 + quad * 8];
#pragma unroll
        for (int i = 0; i < 4; i++)
#pragma unroll
            for (int j = 0; j < 4; j++)
                acc[i][j] = MFMA(af[i], bfm[j], acc[i][j]);
        __syncthreads();
    }

#pragma unroll
    for (int j = 0; j < 4; j++) {
        int cg = n0 + wc * 64 + j * 16 + l16;
        float bv = bias[cg];
#pragma unroll
        for (int i = 0; i < 4; i++) {
            int rbase = m0 + wr * 64 + i * 16 + quad * 4;
#pragma unroll
            for (int r = 0; r < 4; r++) {
                int rg = rbase + r;
                if (rg < M) C[(size_t)rg * DMODEL + cg] = acc[i][j][r] + bv;
            }
        }
    }
}

// ---------------------------------- fused RMSNorm (full 1536) + 3D RoPE + pack
__global__ __launch_bounds__(256) void k_norm_rope(const float* __restrict__ Qf,
                                                   const float* __restrict__ Kf,
                                                   const float* __restrict__ Vf,
                                                   const float* __restrict__ qsc,
                                                   const float* __restrict__ ksc,
                                                   const float* __restrict__ ft,
                                                   const float* __restrict__ fh,
                                                   const float* __restrict__ fw,
                                                   unsigned short* __restrict__ qb,
                                                   unsigned short* __restrict__ kb,
                                                   unsigned short* __restrict__ vb) {
    const int n = blockIdx.x;
    const int tid = threadIdx.x, wave = tid >> 6, lane = tid & 63;
    const int t_i = n / 225, rem = n % 225, h_i = rem / 15, w_i = rem % 15;
    const float att_scale = 0.08838834764831845f * 1.4426950408889634f;  // 1/sqrt(128)*log2e

    float2 qv[3], kv[3], vv[3];
    float sq = 0.f, sk = 0.f;
#pragma unroll
    for (int c = 0; c < 3; c++) {
        int p = tid + 256 * c;
        qv[c] = *(const float2*)(Qf + (size_t)n * DMODEL + 2 * p);
        kv[c] = *(const float2*)(Kf + (size_t)n * DMODEL + 2 * p);
        vv[c] = *(const float2*)(Vf + (size_t)n * DMODEL + 2 * p);
        sq += qv[c].x * qv[c].x + qv[c].y * qv[c].y;
        sk += kv[c].x * kv[c].x + kv[c].y * kv[c].y;
    }
#pragma unroll
    for (int off = 32; off >= 1; off >>= 1) {
        sq += __shfl_xor(sq, off, 64);
        sk += __shfl_xor(sk, off, 64);
    }
    __shared__ float red[2][4];
    if (lane == 0) { red[0][wave] = sq; red[1][wave] = sk; }
    __syncthreads();
    sq = red[0][0] + red[0][1] + red[0][2] + red[0][3];
    sk = red[1][0] + red[1][1] + red[1][2] + red[1][3];
    const float rq = rsqrtf(sq * (1.f / 1536.f) + 1e-6f) * att_scale;
    const float rk = rsqrtf(sk * (1.f / 1536.f) + 1e-6f);

#pragma unroll
    for (int c = 0; c < 3; c++) {
        int p = tid + 256 * c;
        int hd = p >> 6, pl = p & 63, dd = 2 * pl;
        float cs, sn;
        if (pl < 22)      { cs = ft[t_i * 44 + 2 * pl];        sn = ft[t_i * 44 + 2 * pl + 1]; }
        else if (pl < 43) { int pp = pl - 22; cs = fh[h_i * 42 + 2 * pp]; sn = fh[h_i * 42 + 2 * pp + 1]; }
        else              { int pp = pl - 43; cs = fw[w_i * 42 + 2 * pp]; sn = fw[w_i * 42 + 2 * pp + 1]; }
        int hidx = hd * 128 + dd;
        float q0 = qv[c].x * rq * qsc[hidx], q1 = qv[c].y * rq * qsc[hidx + 1];
        float k0 = kv[c].x * rk * ksc[hidx], k1 = kv[c].y * rk * ksc[hidx + 1];
        size_t o = ((size_t)hd * N_TOK + n) * HDIM + dd;
        unsigned qo = (unsigned)f2bf(q0 * cs - q1 * sn) | ((unsigned)f2bf(q0 * sn + q1 * cs) << 16);
        unsigned ko = (unsigned)f2bf(k0 * cs - k1 * sn) | ((unsigned)f2bf(k0 * sn + k1 * cs) << 16);
        unsigned vo = (unsigned)f2bf(vv[c].x) | ((unsigned)f2bf(vv[c].y) << 16);
        *(unsigned*)(qb + o) = qo;
        *(unsigned*)(kb + o) = ko;
        *(unsigned*)(vb + o) = vo;
    }
}

// ----------------- transpose V: [head][tok][128] -> [head][128][VT_STRIDE] bf16
__global__ __launch_bounds__(256) void k_transpose_v(const unsigned short* __restrict__ vbi,
                                                     unsigned short* __restrict__ vt) {
    __shared__ unsigned short tile[32][33];
    const int head = blockIdx.z;
    const int t0 = blockIdx.x * 32, d0 = blockIdx.y * 32;
    const int tx = threadIdx.x, ty = threadIdx.y;      // 32 x 8
#pragma unroll
    for (int i = 0; i < 4; i++) {
        int t = t0 + ty + 8 * i;
        tile[ty + 8 * i][tx] = (t < N_TOK) ? vbi[((size_t)head * N_TOK + t) * HDIM + d0 + tx] : 0;
    }
    __syncthreads();
    int t = t0 + tx;                                   // < VT_STRIDE always
#pragma unroll
    for (int i = 0; i < 4; i++)
        vt[((size_t)head * HDIM + d0 + ty + 8 * i) * VT_STRIDE + t] = tile[tx][ty + 8 * i];
}

// ------------- split-KV flash attention, phase-shifted async pipeline (R7)
__global__ __launch_bounds__(256, 4) void k_attn_part(const unsigned short* __restrict__ qb,
                                                      const unsigned short* __restrict__ kb,
                                                      const unsigned short* __restrict__ vt,
                                                      float* __restrict__ Opart,
                                                      float* __restrict__ mbuf,
                                                      float* __restrict__ lbuf) {
    __shared__ __align__(16) unsigned short Ks[64 * 128];   // [key][d]   linear+swz
    __shared__ __align__(16) unsigned short Vs[128 * 64];   // [d][key]   linear+swz
    __shared__ __align__(16) unsigned short Ps[4][16 * 64]; // per-wave P [qrow][key] swz

    // XCD-aware remap (bijective: 1104 = 8*138)
    const int b = blockIdx.x + 46 * (blockIdx.y + 12 * (int)blockIdx.z);
    const int w = (b & 7) * 138 + (b >> 3);
    const int qblk = w % 46;
    const int head = (w / 46) % 12;
    const int z    = w / 552;

    const int tid = threadIdx.x, wave = tid >> 6, lane = tid & 63;
    const int quad = lane >> 4, l16 = lane & 15, x7 = l16 & 7;
    const int q0 = qblk * 64 + wave * 16;
    const unsigned short* qh = qb + (size_t)head * N_TOK * HDIM;
    const unsigned short* kh = kb + (size_t)head * N_TOK * HDIM;
    const unsigned short* vh = vt + (size_t)head * HDIM * VT_STRIDE;
    unsigned short* ps = Ps[wave];

    const int kbeg = z ? KSPLIT : 0;
    const int kend = z ? N_TOK : KSPLIT;
    const int ntile = (kend - kbeg + 63) >> 6;

    int koff[4];
#pragma unroll
    for (int ks = 0; ks < 4; ks++) {
        int c = ks * 4 + quad;
        koff[ks] = ((c & 8) | ((c & 7) ^ x7)) * 8;
    }
    const int pwq = (quad >> 1), pwh = (quad & 1) * 4;

    const int krow = tid >> 4, ksw = tid & 15;
    const int kc = (ksw & 8) | ((ksw & 7) ^ (krow & 7));
    const int vd = tid >> 3, vsw = tid & 7;
    const int vc = vsw ^ (vd & 7);
    const unsigned short* ksrc = kh + (size_t)krow * HDIM + kc * 8;
    const unsigned short* vsrc = vh + (size_t)vd * VT_STRIDE + vc * 8;

    bf16x8 aq[4];
    {
        int qrow = q0 + l16;
        if (qrow < N_TOK) {
#pragma unroll
            for (int ks = 0; ks < 4; ks++)
                aq[ks] = *(const bf16x8*)&qh[(size_t)qrow * HDIM + ks * 32 + quad * 8];
        } else {
#pragma unroll
            for (int ks = 0; ks < 4; ks++) aq[ks] = (bf16x8)(__bf16)0.0f;
        }
    }

    floatx4 oacc[8] = {};
    float m_l = -1e30f;
    float l_l = 0.f;

    {
        const bool part0 = (kbeg + 64 > kend);
        if (!part0) {
#pragma unroll
            for (int i = 0; i < 4; i++)
                gload_lds16(ksrc + (size_t)(kbeg + 16 * i) * HDIM, &Ks[(tid + 256 * i) * 8]);
        } else {
#pragma unroll
            for (int i = 0; i < 4; i++) {
                int gk = kbeg + krow + 16 * i;
                gk = gk < N_TOK ? gk : N_TOK - 1;
                gload_lds16(kh + (size_t)gk * HDIM + kc * 8, &Ks[(tid + 256 * i) * 8]);
            }
        }
#pragma unroll
        for (int i = 0; i < 4; i++)
            gload_lds16(vsrc + (size_t)(32 * i) * VT_STRIDE + kbeg, &Vs[(tid + 256 * i) * 8]);
    }

    for (int t = 0; t < ntile; t++) {
        const int kb0 = kbeg + t * 64;
        const bool fullt = (kb0 + 64 <= kend);
        const bool has_next = (t + 1 < ntile);

        asm volatile("s_waitcnt vmcnt(4)" ::: "memory");
        __builtin_amdgcn_sched_barrier(0);
        __builtin_amdgcn_s_barrier();

        floatx4 sa[4] = {};
        __builtin_amdgcn_s_setprio(1);
#pragma unroll
        for (int j = 0; j < 4; j++)
#pragma unroll
            for (int ks = 0; ks < 4; ks++) {
                bf16x8 bkf = *(const bf16x8*)&Ks[(j * 16 + l16) * HDIM + koff[ks]];
                sa[j] = MFMA(bkf, aq[ks], sa[j]);
            }
        __builtin_amdgcn_s_setprio(0);
        __builtin_amdgcn_s_barrier();

        if (has_next) {
            const int kn = kb0 + 64;
            if (kn + 64 <= kend) {
#pragma unroll
                for (int i = 0; i < 4; i++)
                    gload_lds16(ksrc + (size_t)(kn + 16 * i) * HDIM, &Ks[(tid + 256 * i) * 8]);
            } else {
#pragma unroll
                for (int i = 0; i < 4; i++) {
                    int gk = kn + krow + 16 * i;
                    gk = gk < N_TOK ? gk : N_TOK - 1;
                    gload_lds16(kh + (size_t)gk * HDIM + kc * 8, &Ks[(tid + 256 * i) * 8]);
                }
            }
        }

        float mt;
        if (fullt) {
            float m01 = fmaxf(fmaxf(sa[0][0], sa[0][1]), fmaxf(sa[0][2], sa[0][3]));
            float m23 = fmaxf(fmaxf(sa[1][0], sa[1][1]), fmaxf(sa[1][2], sa[1][3]));
            float m45 = fmaxf(fmaxf(sa[2][0], sa[2][1]), fmaxf(sa[2][2], sa[2][3]));
            float m67 = fmaxf(fmaxf(sa[3][0], sa[3][1]), fmaxf(sa[3][2], sa[3][3]));
            mt = fmaxf(fmaxf(m01, m23), fmaxf(m45, m67));
        } else {
            mt = -1e30f;
            const int kq = kb0 + quad * 4;
#pragma unroll
            for (int j = 0; j < 4; j++)
#pragma unroll
                for (int r = 0; r < 4; r++)
                    mt = fmaxf(mt, (kq + j * 16 + r < kend) ? sa[j][r] : -1e30f);
        }
        mt = fmaxf(mt, __shfl_xor(mt, 16));
        mt = fmaxf(mt, __shfl_xor(mt, 32));

        if (__any(mt > m_l + 8.f)) {
            float mn = fmaxf(m_l, mt);
            float alpha = exp2f(m_l - mn);
            m_l = mn;
            l_l *= alpha;
#pragma unroll
            for (int r = 0; r < 4; r++) {
                float ar = __shfl(alpha, quad * 4 + r, 16);
#pragma unroll
                for (int jd = 0; jd < 8; jd++) oacc[jd][r] *= ar;
            }
        }

        if (fullt) {
#pragma unroll
            for (int j = 0; j < 4; j++) {
                float p0 = exp2f(sa[j][0] - m_l), p1 = exp2f(sa[j][1] - m_l);
                float p2 = exp2f(sa[j][2] - m_l), p3 = exp2f(sa[j][3] - m_l);
                l_l += (p0 + p1) + (p2 + p3);
                uint2 wv;
                wv.x = (unsigned)__builtin_bit_cast(unsigned short, (__bf16)p0) |
                       ((unsigned)__builtin_bit_cast(unsigned short, (__bf16)p1) << 16);
                wv.y = (unsigned)__builtin_bit_cast(unsigned short, (__bf16)p2) |
                       ((unsigned)__builtin_bit_cast(unsigned short, (__bf16)p3) << 16);
                *(uint2*)&ps[l16 * 64 + (((j * 2 + pwq) ^ x7) << 3) + pwh] = wv;
            }
        } else {
            const int kq = kb0 + quad * 4;
#pragma unroll
            for (int j = 0; j < 4; j++) {
                float p[4];
#pragma unroll
                for (int r = 0; r < 4; r++) {
                    p[r] = (kq + j * 16 + r < kend) ? exp2f(sa[j][r] - m_l) : 0.f;
                    l_l += p[r];
                }
                uint2 wv;
                wv.x = (unsigned)__builtin_bit_cast(unsigned short, (__bf16)p[0]) |
                       ((unsigned)__builtin_bit_cast(unsigned short, (__bf16)p[1]) << 16);
                wv.y = (unsigned)__builtin_bit_cast(unsigned short, (__bf16)p[2]) |
                       ((unsigned)__builtin_bit_cast(unsigned short, (__bf16)p[3]) << 16);
                *(uint2*)&ps[l16 * 64 + (((j * 2 + pwq) ^ x7) << 3) + pwh] = wv;
            }
        }

        if (has_next) { asm volatile("s_waitcnt vmcnt(4)" ::: "memory"); }
        else          { asm volatile("s_waitcnt vmcnt(0)" ::: "memory"); }
        __builtin_amdgcn_sched_barrier(0);
        __builtin_amdgcn_s_barrier();

        __builtin_amdgcn_s_setprio(1);
#pragma unroll
        for (int ks = 0; ks < 2; ks++) {
            bf16x8 ap = *(const bf16x8*)&ps[l16 * 64 + koff[ks]];
#pragma unroll
            for (int jd = 0; jd < 8; jd++) {
                bf16x8 bvf = *(const bf16x8*)&Vs[(jd * 16 + l16) * 64 + koff[ks]];
                oacc[jd] = MFMA(ap, bvf, oacc[jd]);
            }
        }
        __builtin_amdgcn_s_setprio(0);
        __builtin_amdgcn_s_barrier();

        if (has_next) {
            const int kn = kb0 + 64;
#pragma unroll
            for (int i = 0; i < 4; i++)
                gload_lds16(vsrc + (size_t)(32 * i) * VT_STRIDE + kn, &Vs[(tid + 256 * i) * 8]);
        }
    }

    l_l += __shfl_xor(l_l, 16);
    l_l += __shfl_xor(l_l, 32);

#pragma unroll
    for (int r = 0; r < 4; r++) {
        int rg = q0 + quad * 4 + r;
        if (rg < N_TOK) {
            size_t rbase = ((size_t)(z * NHEAD + head) * N_TOK + rg) * HDIM;
#pragma unroll
            for (int jd = 0; jd < 8; jd++)
                Opart[rbase + jd * 16 + l16] = oacc[jd][r];
        }
    }
    if (quad == 0 && q0 + l16 < N_TOK) {
        int mi = (z * NHEAD + head) * N_TOK + q0 + l16;
        mbuf[mi] = m_l;
        lbuf[mi] = l_l;
    }
}

// ----------------------------------------------- combine the two KV splits
__global__ __launch_bounds__(256) void k_combine(const float* __restrict__ Opart,
                                                 const float* __restrict__ mbuf,
                                                 const float* __restrict__ lbuf,
                                                 unsigned short* __restrict__ ab) {
    const int R = NHEAD * N_TOK;
    int r = blockIdx.x * 8 + (threadIdx.x >> 5);
    if (r >= R) return;
    int l32 = threadIdx.x & 31;
    float m0 = mbuf[r], m1 = mbuf[R + r];
    float l0 = lbuf[r], l1 = lbuf[R + r];
    float m = fmaxf(m0, m1);
    float w0 = exp2f(m0 - m), w1 = exp2f(m1 - m);
    float inv = 1.f / (l0 * w0 + l1 * w1);
    w0 *= inv; w1 *= inv;
    float4 a = *(const float4*)&Opart[(size_t)r * HDIM + l32 * 4];
    float4 b = *(const float4*)&Opart[((size_t)R + r) * HDIM + l32 * 4];
    int head = r / N_TOK, tok = r % N_TOK;
    unsigned short* o = ab + (size_t)tok * DMODEL + head * HDIM + l32 * 4;
    uint2 pk;
    pk.x = (unsigned)f2bf(a.x * w0 + b.x * w1) | ((unsigned)f2bf(a.y * w0 + b.y * w1) << 16);
    pk.y = (unsigned)f2bf(a.z * w0 + b.z * w1) | ((unsigned)f2bf(a.w * w0 + b.w * w1) << 16);
    *(uint2*)o = pk;
}

// ---------------------------------------------------------------------------
extern "C" void kernel_launch(void* const* d_in, const int* in_sizes, int n_in,
                              void* d_out, int out_size, void* d_ws, size_t ws_size,
                              hipStream_t stream) {
    const float* x   = (const float*)d_in[0];
    const float* Wq  = (const float*)d_in[1];
    const float* bq  = (const float*)d_in[2];
    const float* Wk  = (const float*)d_in[3];
    const float* bk  = (const float*)d_in[4];
    const float* Wv  = (const float*)d_in[5];
    const float* bv  = (const float*)d_in[6];
    const float* Wo  = (const float*)d_in[7];
    const float* bo  = (const float*)d_in[8];
    const float* qsc = (const float*)d_in[9];
    const float* ksc = (const float*)d_in[10];
    const float* ft  = (const float*)d_in[11];
    const float* fh  = (const float*)d_in[12];
    const float* fw  = (const float*)d_in[13];

    // Layout note: ab sits BEFORE the fp32 region so the O-GEMM's A-tile
    // over-reads (rows 2925..2943) land inside d_ws, never past its end.
    // QKV-GEMM A-overreads (rows 2925..3071, 451KB) land in Wt — also safe.
    char* ws = (char*)d_ws;
    unsigned short* xb   = (unsigned short*)ws; ws += (size_t)N_TOK * DMODEL * 2;          // 8,985,600
    unsigned short* Wt   = (unsigned short*)ws; ws += (size_t)4 * DMODEL * DMODEL * 2;     // 18,874,368
    unsigned short* ab   = (unsigned short*)ws; ws += (size_t)N_TOK * DMODEL * 2;          // 8,985,600
    char* qkvf_region    = ws;                  ws += (size_t)3 * N_TOK * DMODEL * 4;      // 53,913,600
    unsigned short* qkvb = (unsigned short*)ws; ws += (size_t)3 * N_TOK * DMODEL * 2;      // 26,956,800

    float* Qf = (float*)qkvf_region;
    float* Kf = Qf + (size_t)N_TOK * DMODEL;
    float* Vf = Qf + (size_t)2 * N_TOK * DMODEL;
    float* Opart = (float*)qkvf_region;
    float* mbuf  = Opart + (size_t)2 * NHEAD * N_TOK * HDIM;
    float* lbuf  = mbuf + (size_t)2 * NHEAD * N_TOK;
    unsigned short* vtp = (unsigned short*)(lbuf + (size_t)2 * NHEAD * N_TOK);

    unsigned short* qbp = qkvb;
    unsigned short* kbp = qkvb + (size_t)N_TOK * DMODEL;
    unsigned short* vbp = qkvb + (size_t)2 * N_TOK * DMODEL;

    const int nelem = N_TOK * DMODEL;
    k_convert_x<<<(nelem / 4 + 255) / 256, 256, 0, stream>>>(x, xb, nelem);
    k_transpose_w<<<dim3(48, 48, 4), dim3(32, 8), 0, stream>>>(Wq, Wk, Wv, Wo, Wt);
    k_gemm_qkv<<<dim3(6, 12, 3), 512, 0, stream>>>(xb, Wt, bq, bk, bv, Qf, N_TOK);
    k_norm_rope<<<N_TOK, 256, 0, stream>>>(Qf, Kf, Vf, qsc, ksc, ft, fh, fw, qbp, kbp, vbp);
    k_transpose_v<<<dim3(92, 4, NHEAD), dim3(32, 8), 0, stream>>>(vbp, vtp);
    k_attn_part<<<dim3(46, NHEAD, 2), 256, 0, stream>>>(qbp, kbp, vtp, Opart, mbuf, lbuf);
    k_combine<<<(NHEAD * N_TOK + 7) / 8, 256, 0, stream>>>(Opart, mbuf, lbuf, ab);
    k_gemm<<<dim3(12, 23, 1), 256, 0, stream>>>(ab, Wt + (size_t)3 * DMODEL * DMODEL,
                                                bo, bo, bo, (float*)d_out, N_TOK);
}

// Round 8
// 352.303 us; speedup vs baseline: 1.1183x; 1.0093x over previous
//
#include <hip/hip_runtime.h>

// ---------------------------------------------------------------------------
// MultiHeadAttention (B=1, N=2925, D_MODEL=1536, 12 heads x 128) on gfx950.
// convert/transpose -> QKV bf16 GEMM (256x256 double-buffered counted-vmcnt
// pipeline, T2 swizzle) -> RMSNorm+3D RoPE (Q,K only) -> V fp32->bf16
// transpose -> NO-SPLIT flash attention (swapped-QK^T, phase-shifted staging,
// epilogue normalization, direct bf16 output) -> O GEMM (128^2).
// ---------------------------------------------------------------------------

#define N_TOK 2925
#define DMODEL 1536
#define NHEAD 12
#define HDIM 128
#define VT_STRIDE 2944        // N_TOK padded to x64; pad MUST be zeroed (NaN hazard)

typedef __attribute__((ext_vector_type(8))) __bf16 bf16x8;
typedef __attribute__((ext_vector_type(4))) float floatx4;

#define MFMA(a, b, c) __builtin_amdgcn_mfma_f32_16x16x32_bf16((a), (b), (c), 0, 0, 0)

static __device__ __forceinline__ unsigned short f2bf(float f) {
    unsigned u = __builtin_bit_cast(unsigned, f);
    return (unsigned short)((u + 0x7fffu + ((u >> 16) & 1u)) >> 16);
}

// async global->LDS 16B/lane (emits global_load_lds_dwordx4).
// LDS dest MUST be wave-uniform-base + lane*16.
static __device__ __forceinline__ void gload_lds16(const unsigned short* g, unsigned short* l) {
    __builtin_amdgcn_global_load_lds((const __attribute__((address_space(1))) void*)g,
                                     (__attribute__((address_space(3))) void*)l, 16, 0, 0);
}

// ---------------------------------------------------------------- convert x
__global__ __launch_bounds__(256) void k_convert_x(const float* __restrict__ x,
                                                   unsigned short* __restrict__ xb, int n) {
    int i = (blockIdx.x * 256 + threadIdx.x) * 4;
    if (i < n) {
        float4 v = *(const float4*)(x + i);
        uint2 o;
        o.x = (unsigned)f2bf(v.x) | ((unsigned)f2bf(v.y) << 16);
        o.y = (unsigned)f2bf(v.z) | ((unsigned)f2bf(v.w) << 16);
        *(uint2*)(xb + i) = o;
    }
}

// ---------------------------------------------- transpose W [k][n] -> Wt [n][k] bf16
__global__ __launch_bounds__(256) void k_transpose_w(const float* __restrict__ W0,
                                                     const float* __restrict__ W1,
                                                     const float* __restrict__ W2,
                                                     const float* __restrict__ W3,
                                                     unsigned short* __restrict__ Wt) {
    __shared__ float tile[32][33];
    const float* W = blockIdx.z == 0 ? W0 : blockIdx.z == 1 ? W1 : blockIdx.z == 2 ? W2 : W3;
    unsigned short* out = Wt + (size_t)blockIdx.z * DMODEL * DMODEL;
    int tx = threadIdx.x, ty = threadIdx.y;           // 32 x 8
    int bx = blockIdx.x * 32, by = blockIdx.y * 32;
#pragma unroll
    for (int i = 0; i < 4; i++)
        tile[ty + 8 * i][tx] = W[(size_t)(by + ty + 8 * i) * DMODEL + bx + tx];
    __syncthreads();
#pragma unroll
    for (int i = 0; i < 4; i++)
        out[(size_t)(bx + ty + 8 * i) * DMODEL + by + tx] = f2bf(tile[tx][ty + 8 * i]);
}

// ---------------------- QKV GEMM: 256x256 tile, BK=64, 8 waves, dbuf pipeline
// LDS 128 KiB (2 bufs x (A,B) x 256x64 bf16), XOR swizzle chunk^=(row&7) on
// both sides.  Per K-tile 4 phases; staging spread {B-top,B-bot,A-lo,A-hi}
// (A halves interleaved).  Counted vmcnt(2) at W1/W2; raw s_barrier.
__global__ __launch_bounds__(512, 2) void k_gemm_qkv(const unsigned short* __restrict__ A,
                                                     const unsigned short* __restrict__ BtBase,
                                                     const float* __restrict__ b0,
                                                     const float* __restrict__ b1,
                                                     const float* __restrict__ b2,
                                                     float* __restrict__ Cbase, int M) {
    __shared__ __align__(16) unsigned short As[2][256 * 64];   // 2 x 32 KiB
    __shared__ __align__(16) unsigned short Bs[2][256 * 64];   // 2 x 32 KiB

    // XCD swizzle: nb = 216 = 8*27 exact
    const int blin = blockIdx.x + 6 * (blockIdx.y + 12 * (int)blockIdx.z);
    const int wg = (blin & 7) * 27 + (blin >> 3);
    const int z = wg / 72, rem = wg % 72, mt = rem / 6, ntile = rem % 6;
    const unsigned short* Bt = BtBase + (size_t)z * DMODEL * DMODEL;
    const float* bias = (z == 0) ? b0 : (z == 1) ? b1 : b2;
    float* C = Cbase + (size_t)z * M * DMODEL;
    const int m0 = mt * 256, n0 = ntile * 256;

    const int tid = threadIdx.x;
    const int wave = tid >> 6, lane = tid & 63, quad = lane >> 4, l16 = lane & 15;
    const int x7 = l16 & 7;
    const int wm = wave >> 2, wn = wave & 3;

    const int koff0 = ((quad) ^ x7) * 8;
    const int koff1 = ((4 + quad) ^ x7) * 8;
    const int sl = tid & 7;

    floatx4 acc[8][4] = {};

    const unsigned short* Abase = A + (size_t)m0 * DMODEL;
    const unsigned short* Bbase = Bt + (size_t)n0 * DMODEL;

    auto stageB = [&](int buf, int h, int kt) {
#pragma unroll
        for (int i = 0; i < 2; i++) {
            int d = tid + 512 * i;
            int row = h * 128 + (d >> 3);
            int c = sl ^ (row & 7);
            gload_lds16(Bbase + (size_t)row * DMODEL + kt * 64 + c * 8,
                        &Bs[buf][(row * 8 + sl) * 8]);
        }
    };
    auto stageA = [&](int buf, int h, int kt) {
#pragma unroll
        for (int i = 0; i < 2; i++) {
            int d = tid + 512 * i;
            int r7 = d >> 3;
            int row = (r7 & 63) + h * 64 + (r7 >> 6) * 128;
            int c = sl ^ (row & 7);
            gload_lds16(Abase + (size_t)row * DMODEL + kt * 64 + c * 8,
                        &As[buf][(row * 8 + sl) * 8]);
        }
    };

    stageB(0, 0, 0); stageB(0, 1, 0); stageA(0, 0, 0); stageA(0, 1, 0);

    const int NT = DMODEL / 64;                                  // 24
    for (int t = 0; t < NT; t++) {
        const int c = t & 1, sb = c ^ 1;
        const int ts = (t + 1 < NT) ? t + 1 : NT - 1;

        asm volatile("s_waitcnt vmcnt(2)" ::: "memory");
        __builtin_amdgcn_sched_barrier(0);
        __builtin_amdgcn_s_barrier();

        bf16x8 af[4], bfm[4];
#pragma unroll
        for (int m = 0; m < 4; m++)
            af[m] = *(const bf16x8*)&As[c][(wm * 128 + m * 16 + l16) * 64 + koff0];
#pragma unroll
        for (int n = 0; n < 4; n++)
            bfm[n] = *(const bf16x8*)&Bs[c][(wn * 64 + n * 16 + l16) * 64 + koff0];
        stageB(sb, 0, ts);
        __builtin_amdgcn_s_barrier();
        __builtin_amdgcn_s_setprio(1);
#pragma unroll
        for (int m = 0; m < 4; m++)
#pragma unroll
            for (int n = 0; n < 4; n++)
                acc[m][n] = MFMA(af[m], bfm[n], acc[m][n]);
        __builtin_amdgcn_s_setprio(0);
        __builtin_amdgcn_sched_barrier(0);

        asm volatile("s_waitcnt vmcnt(2)" ::: "memory");
        __builtin_amdgcn_sched_barrier(0);
        __builtin_amdgcn_s_barrier();

        bf16x8 af2[4];
#pragma unroll
        for (int m = 0; m < 4; m++)
            af2[m] = *(const bf16x8*)&As[c][(wm * 128 + 64 + m * 16 + l16) * 64 + koff0];
        stageB(sb, 1, ts);
        __builtin_amdgcn_s_barrier();
        __builtin_amdgcn_s_setprio(1);
#pragma unroll
        for (int m = 0; m < 4; m++)
#pragma unroll
            for (int n = 0; n < 4; n++)
                acc[4 + m][n] = MFMA(af2[m], bfm[n], acc[4 + m][n]);
        __builtin_amdgcn_s_setprio(0);
        __builtin_amdgcn_sched_barrier(0);

#pragma unroll
        for (int m = 0; m < 4; m++)
            af[m] = *(const bf16x8*)&As[c][(wm * 128 + m * 16 + l16) * 64 + koff1];
#pragma unroll
        for (int n = 0; n < 4; n++)
            bfm[n] = *(const bf16x8*)&Bs[c][(wn * 64 + n * 16 + l16) * 64 + koff1];
        stageA(sb, 0, ts);
        __builtin_amdgcn_s_barrier();
        __builtin_amdgcn_s_setprio(1);
#pragma unroll
        for (int m = 0; m < 4; m++)
#pragma unroll
            for (int n = 0; n < 4; n++)
                acc[m][n] = MFMA(af[m], bfm[n], acc[m][n]);
        __builtin_amdgcn_s_setprio(0);
        __builtin_amdgcn_sched_barrier(0);

#pragma unroll
        for (int m = 0; m < 4; m++)
            af2[m] = *(const bf16x8*)&As[c][(wm * 128 + 64 + m * 16 + l16) * 64 + koff1];
        stageA(sb, 1, ts);
        __builtin_amdgcn_s_barrier();
        __builtin_amdgcn_s_setprio(1);
#pragma unroll
        for (int m = 0; m < 4; m++)
#pragma unroll
            for (int n = 0; n < 4; n++)
                acc[4 + m][n] = MFMA(af2[m], bfm[n], acc[4 + m][n]);
        __builtin_amdgcn_s_setprio(0);
        __builtin_amdgcn_sched_barrier(0);
    }

#pragma unroll
    for (int n = 0; n < 4; n++) {
        int cg = n0 + wn * 64 + n * 16 + l16;
        float bv = bias[cg];
#pragma unroll
        for (int m = 0; m < 8; m++) {
            int rbase = m0 + wm * 128 + m * 16 + quad * 4;
#pragma unroll
            for (int r = 0; r < 4; r++) {
                int rg = rbase + r;
                if (rg < M) C[(size_t)rg * DMODEL + cg] = acc[m][n][r] + bv;
            }
        }
    }
}

// ------------------------------------------------------------ bf16 MFMA GEMM
// m97 structure (used for the O projection): unpadded stride-32 LDS tiles.
__global__ __launch_bounds__(256, 3) void k_gemm(const unsigned short* __restrict__ A,
                                                 const unsigned short* __restrict__ BtBase,
                                                 const float* __restrict__ b0,
                                                 const float* __restrict__ b1,
                                                 const float* __restrict__ b2,
                                                 float* __restrict__ Cbase, int M) {
    const int nbx = gridDim.x, nxy = gridDim.x * gridDim.y;
    const int nb = nxy * gridDim.z;
    const int blin = blockIdx.x + nbx * (blockIdx.y + gridDim.y * blockIdx.z);
    const int q8 = nb >> 3, r8 = nb & 7, xcd = blin & 7, idx = blin >> 3;
    const int wg = (xcd < r8) ? xcd * (q8 + 1) + idx
                              : r8 * (q8 + 1) + (xcd - r8) * q8 + idx;
    const int z = wg / nxy;
    const int rem = wg % nxy;
    const int bym = rem / nbx, bxn = rem % nbx;

    const unsigned short* Bt = BtBase + (size_t)z * DMODEL * DMODEL;
    const float* bias = (z == 0) ? b0 : (z == 1) ? b1 : b2;
    float* C = Cbase + (size_t)z * M * DMODEL;

    __shared__ __align__(16) unsigned short As[128 * 32];
    __shared__ __align__(16) unsigned short Bs[128 * 32];

    const int tid = threadIdx.x;
    const int wave = tid >> 6, lane = tid & 63, quad = lane >> 4, l16 = lane & 15;
    const int wr = wave >> 1, wc = wave & 1;
    const int m0 = bym * 128, n0 = bxn * 128;
    const int r4 = tid >> 2, c4 = (tid & 3) * 8;

    floatx4 acc[4][4] = {};

    for (int k0 = 0; k0 < DMODEL; k0 += 32) {
        gload_lds16(A + (size_t)(m0 + r4) * DMODEL + k0 + c4,       &As[r4 * 32 + c4]);
        gload_lds16(A + (size_t)(m0 + r4 + 64) * DMODEL + k0 + c4,  &As[(r4 + 64) * 32 + c4]);
        gload_lds16(Bt + (size_t)(n0 + r4) * DMODEL + k0 + c4,      &Bs[r4 * 32 + c4]);
        gload_lds16(Bt + (size_t)(n0 + r4 + 64) * DMODEL + k0 + c4, &Bs[(r4 + 64) * 32 + c4]);
        __syncthreads();

        bf16x8 af[4], bfm[4];
#pragma unroll
        for (int i = 0; i < 4; i++)
            af[i] = *(const bf16x8*)&As[(wr * 64 + i * 16 + l16) * 32 + quad * 8];
#pragma unroll
        for (int j = 0; j < 4; j++)
            bfm[j] = *(const bf16x8*)&Bs[(wc * 64 + j * 16 + l16) * 32 + quad * 8];
#pragma unroll
        for (int i = 0; i < 4; i++)
#pragma unroll
            for (int j = 0; j < 4; j++)
                acc[i][j] = MFMA(af[i], bfm[j], acc[i][j]);
        __syncthreads();
    }

#pragma unroll
    for (int j = 0; j < 4; j++) {
        int cg = n0 + wc * 64 + j * 16 + l16;
        float bv = bias[cg];
#pragma unroll
        for (int i = 0; i < 4; i++) {
            int rbase = m0 + wr * 64 + i * 16 + quad * 4;
#pragma unroll
            for (int r = 0; r < 4; r++) {
                int rg = rbase + r;
                if (rg < M) C[(size_t)rg * DMODEL + cg] = acc[i][j][r] + bv;
            }
        }
    }
}

// ------------------- fused RMSNorm (full 1536) + 3D RoPE + pack (Q,K only)
// q pre-scaled by (1/sqrt(HDIM))*log2(e) -> softmax runs in exp2 domain.
__global__ __launch_bounds__(256) void k_norm_rope(const float* __restrict__ Qf,
                                                   const float* __restrict__ Kf,
                                                   const float* __restrict__ qsc,
                                                   const float* __restrict__ ksc,
                                                   const float* __restrict__ ft,
                                                   const float* __restrict__ fh,
                                                   const float* __restrict__ fw,
                                                   unsigned short* __restrict__ qb,
                                                   unsigned short* __restrict__ kb) {
    const int n = blockIdx.x;
    const int tid = threadIdx.x, wave = tid >> 6, lane = tid & 63;
    const int t_i = n / 225, rem = n % 225, h_i = rem / 15, w_i = rem % 15;
    const float att_scale = 0.08838834764831845f * 1.4426950408889634f;  // 1/sqrt(128)*log2e

    float2 qv[3], kv[3];
    float sq = 0.f, sk = 0.f;
#pragma unroll
    for (int c = 0; c < 3; c++) {
        int p = tid + 256 * c;
        qv[c] = *(const float2*)(Qf + (size_t)n * DMODEL + 2 * p);
        kv[c] = *(const float2*)(Kf + (size_t)n * DMODEL + 2 * p);
        sq += qv[c].x * qv[c].x + qv[c].y * qv[c].y;
        sk += kv[c].x * kv[c].x + kv[c].y * kv[c].y;
    }
#pragma unroll
    for (int off = 32; off >= 1; off >>= 1) {
        sq += __shfl_xor(sq, off, 64);
        sk += __shfl_xor(sk, off, 64);
    }
    __shared__ float red[2][4];
    if (lane == 0) { red[0][wave] = sq; red[1][wave] = sk; }
    __syncthreads();
    sq = red[0][0] + red[0][1] + red[0][2] + red[0][3];
    sk = red[1][0] + red[1][1] + red[1][2] + red[1][3];
    const float rq = rsqrtf(sq * (1.f / 1536.f) + 1e-6f) * att_scale;
    const float rk = rsqrtf(sk * (1.f / 1536.f) + 1e-6f);

#pragma unroll
    for (int c = 0; c < 3; c++) {
        int p = tid + 256 * c;
        int hd = p >> 6, pl = p & 63, dd = 2 * pl;
        float cs, sn;
        if (pl < 22)      { cs = ft[t_i * 44 + 2 * pl];        sn = ft[t_i * 44 + 2 * pl + 1]; }
        else if (pl < 43) { int pp = pl - 22; cs = fh[h_i * 42 + 2 * pp]; sn = fh[h_i * 42 + 2 * pp + 1]; }
        else              { int pp = pl - 43; cs = fw[w_i * 42 + 2 * pp]; sn = fw[w_i * 42 + 2 * pp + 1]; }
        int hidx = hd * 128 + dd;
        float q0 = qv[c].x * rq * qsc[hidx], q1 = qv[c].y * rq * qsc[hidx + 1];
        float k0 = kv[c].x * rk * ksc[hidx], k1 = kv[c].y * rk * ksc[hidx + 1];
        size_t o = ((size_t)hd * N_TOK + n) * HDIM + dd;
        unsigned qo = (unsigned)f2bf(q0 * cs - q1 * sn) | ((unsigned)f2bf(q0 * sn + q1 * cs) << 16);
        unsigned ko = (unsigned)f2bf(k0 * cs - k1 * sn) | ((unsigned)f2bf(k0 * sn + k1 * cs) << 16);
        *(unsigned*)(qb + o) = qo;
        *(unsigned*)(kb + o) = ko;
    }
}

// -------- transpose V: Vf fp32 [tok][1536] -> vt bf16 [head][128][VT_STRIDE]
// Pad columns [N_TOK, VT_STRIDE) are WRITTEN AS ZERO (recycled region NaN hazard).
__global__ __launch_bounds__(256) void k_transpose_vf(const float* __restrict__ Vf,
                                                      unsigned short* __restrict__ vt) {
    __shared__ float tile[32][33];
    const int head = blockIdx.z;
    const int t0 = blockIdx.x * 32, d0 = blockIdx.y * 32;
    const int tx = threadIdx.x, ty = threadIdx.y;      // 32 x 8
#pragma unroll
    for (int i = 0; i < 4; i++) {
        int t = t0 + ty + 8 * i;
        tile[ty + 8 * i][tx] = (t < N_TOK) ? Vf[(size_t)t * DMODEL + head * HDIM + d0 + tx] : 0.f;
    }
    __syncthreads();
    int t = t0 + tx;                                   // < VT_STRIDE always
#pragma unroll
    for (int i = 0; i < 4; i++)
        vt[((size_t)head * HDIM + d0 + ty + 8 * i) * VT_STRIDE + t] = f2bf(tile[tx][ty + 8 * i]);
}

// ---------------- NO-SPLIT flash attention, phase-shifted async pipeline (R8)
// Block = (q-tile 64 rows, head). 4 waves x 16 rows each. 46 KV tiles of 64.
// exp2-domain softmax (log2e folded into q).  Swapped QK^T: sa[j][r] =
// S[qrow=l16][key=j*16+quad*4+r] -> lane-local softmax, b64 P writes.
// Epilogue: normalize by 1/l and write bf16 ab directly (no combine pass).
//
// Pipeline (counted vmcnt, raw barriers):
//   top:   vmcnt(4) [drain Q+K(t), V(t) in flight] ; barrier ; QK
//   post-QK barrier ; issue K(t+1)
//   pre-PV: vmcnt(4) [drain V(t), K(t+1) in flight] ; barrier ; PV
//   post-PV barrier ; issue V(t+1)
// XCD swizzle: 552 blocks = 8 x 69 (exact).  All 552 blocks co-resident
// (capacity 4/CU x 256 = 1024) -> single dispatch round.
// LDS = 16384 (K) + 16384 (V^T) + 8192 (P) = 40960 -> 4 blocks/CU.
__global__ __launch_bounds__(256, 4) void k_attn_part(const unsigned short* __restrict__ qb,
                                                      const unsigned short* __restrict__ kb,
                                                      const unsigned short* __restrict__ vt,
                                                      unsigned short* __restrict__ ab) {
    __shared__ __align__(16) unsigned short Ks[64 * 128];   // [key][d]   linear+swz
    __shared__ __align__(16) unsigned short Vs[128 * 64];   // [d][key]   linear+swz
    __shared__ __align__(16) unsigned short Ps[4][16 * 64]; // per-wave P [qrow][key] swz

    // XCD-aware remap (bijective: 552 = 8*69)
    const int b = blockIdx.x + 46 * (int)blockIdx.y;
    const int w = (b & 7) * 69 + (b >> 3);
    const int qblk = w % 46;
    const int head = w / 46;

    const int tid = threadIdx.x, wave = tid >> 6, lane = tid & 63;
    const int quad = lane >> 4, l16 = lane & 15, x7 = l16 & 7;
    const int q0 = qblk * 64 + wave * 16;
    const unsigned short* qh = qb + (size_t)head * N_TOK * HDIM;
    const unsigned short* kh = kb + (size_t)head * N_TOK * HDIM;
    const unsigned short* vh = vt + (size_t)head * HDIM * VT_STRIDE;
    unsigned short* ps = Ps[wave];

    const int ntile = (N_TOK + 63) >> 6;               // 46 (last tile partial: 45 keys)

    // swizzled 16B-chunk read offsets (in shorts); chunk c = ks*4+quad, row&7 = l16&7.
    int koff[4];
#pragma unroll
    for (int ks = 0; ks < 4; ks++) {
        int c = ks * 4 + quad;
        koff[ks] = ((c & 8) | ((c & 7) ^ x7)) * 8;
    }
    // P write base: row l16, chunk (j*2 + (quad>>1)) ^ x7, half (quad&1).
    const int pwq = (quad >> 1), pwh = (quad & 1) * 4;

    // staging: thread covers LDS chunk (tid + 256*i), i=0..3 (lane-linear dest).
    const int krow = tid >> 4, ksw = tid & 15;
    const int kc = (ksw & 8) | ((ksw & 7) ^ (krow & 7));   // (krow+16i)&7 == krow&7
    const int vd = tid >> 3, vsw = tid & 7;
    const int vc = vsw ^ (vd & 7);                          // (vd+32i)&7 == vd&7
    const unsigned short* ksrc = kh + (size_t)krow * HDIM + kc * 8;
    const unsigned short* vsrc = vh + (size_t)vd * VT_STRIDE + vc * 8;

    // Q fragments (loaded FIRST: oldest vmcnt entries; ledger robust whether
    // or not the guarded loads issue — K(t) is always the oldest 4 after them)
    bf16x8 aq[4];
    {
        int qrow = q0 + l16;
        if (qrow < N_TOK) {
#pragma unroll
            for (int ks = 0; ks < 4; ks++)
                aq[ks] = *(const bf16x8*)&qh[(size_t)qrow * HDIM + ks * 32 + quad * 8];
        } else {
#pragma unroll
            for (int ks = 0; ks < 4; ks++) aq[ks] = (bf16x8)(__bf16)0.0f;
        }
    }

    floatx4 oacc[8] = {};
    float m_l = -1e30f;   // running max of lane's own q-row (l16)
    float l_l = 0.f;      // per-lane PARTIAL sum (reduced over quads at end)

    // ---- prologue: issue K(0) then V(0)  (tile 0 is always full)
#pragma unroll
    for (int i = 0; i < 4; i++)
        gload_lds16(ksrc + (size_t)(16 * i) * HDIM, &Ks[(tid + 256 * i) * 8]);
#pragma unroll
    for (int i = 0; i < 4; i++)
        gload_lds16(vsrc + (size_t)(32 * i) * VT_STRIDE, &Vs[(tid + 256 * i) * 8]);

    for (int t = 0; t < ntile; t++) {
        const int kb0 = t * 64;
        const bool fullt = (kb0 + 64 <= N_TOK);        // false only for t=45
        const bool has_next = (t + 1 < ntile);

        // ---- K(t) ready: drain all but the 4 newest (V(t)); cross-wave barrier
        asm volatile("s_waitcnt vmcnt(4)" ::: "memory");
        __builtin_amdgcn_sched_barrier(0);
        __builtin_amdgcn_s_barrier();

        // ---- S^T = K Q^T : sa[j][r] = S[l16][kb0 + j*16 + quad*4 + r]
        floatx4 sa[4] = {};
        __builtin_amdgcn_s_setprio(1);
#pragma unroll
        for (int j = 0; j < 4; j++)
#pragma unroll
            for (int ks = 0; ks < 4; ks++) {
                bf16x8 bkf = *(const bf16x8*)&Ks[(j * 16 + l16) * HDIM + koff[ks]];
                sa[j] = MFMA(bkf, aq[ks], sa[j]);
            }
        __builtin_amdgcn_s_setprio(0);
        __builtin_amdgcn_s_barrier();            // all waves done reading Ks

        // ---- issue K(t+1) into Ks (lands while we do softmax+PV+next wait)
        if (has_next) {
            const int kn = kb0 + 64;
            if (kn + 64 <= N_TOK) {
#pragma unroll
                for (int i = 0; i < 4; i++)
                    gload_lds16(ksrc + (size_t)(kn + 16 * i) * HDIM, &Ks[(tid + 256 * i) * 8]);
            } else {
#pragma unroll
                for (int i = 0; i < 4; i++) {
                    int gk = kn + krow + 16 * i;
                    gk = gk < N_TOK ? gk : N_TOK - 1;
                    gload_lds16(kh + (size_t)gk * HDIM + kc * 8, &Ks[(tid + 256 * i) * 8]);
                }
            }
        }

        // ---- per-lane tile max over its 16 S values, 2 quad shuffles
        float mt;
        if (fullt) {
            float m01 = fmaxf(fmaxf(sa[0][0], sa[0][1]), fmaxf(sa[0][2], sa[0][3]));
            float m23 = fmaxf(fmaxf(sa[1][0], sa[1][1]), fmaxf(sa[1][2], sa[1][3]));
            float m45 = fmaxf(fmaxf(sa[2][0], sa[2][1]), fmaxf(sa[2][2], sa[2][3]));
            float m67 = fmaxf(fmaxf(sa[3][0], sa[3][1]), fmaxf(sa[3][2], sa[3][3]));
            mt = fmaxf(fmaxf(m01, m23), fmaxf(m45, m67));
        } else {
            mt = -1e30f;
            const int kq = kb0 + quad * 4;
#pragma unroll
            for (int j = 0; j < 4; j++)
#pragma unroll
                for (int r = 0; r < 4; r++)
                    mt = fmaxf(mt, (kq + j * 16 + r < N_TOK) ? sa[j][r] : -1e30f);
        }
        mt = fmaxf(mt, __shfl_xor(mt, 16));
        mt = fmaxf(mt, __shfl_xor(mt, 32));

        // ---- defer-max (T13, THR=8 in exp2 domain)
        if (__any(mt > m_l + 8.f)) {
            float mn = fmaxf(m_l, mt);
            float alpha = exp2f(m_l - mn);
            m_l = mn;
            l_l *= alpha;
#pragma unroll
            for (int r = 0; r < 4; r++) {
                float ar = __shfl(alpha, quad * 4 + r, 16);
#pragma unroll
                for (int jd = 0; jd < 8; jd++) oacc[jd][r] *= ar;
            }
        }

        // ---- P = exp2(S - m): 4 keys/lane/j, packed bf16 -> ds_write_b64
        if (fullt) {
#pragma unroll
            for (int j = 0; j < 4; j++) {
                float p0 = exp2f(sa[j][0] - m_l), p1 = exp2f(sa[j][1] - m_l);
                float p2 = exp2f(sa[j][2] - m_l), p3 = exp2f(sa[j][3] - m_l);
                l_l += (p0 + p1) + (p2 + p3);
                uint2 wv;
                wv.x = (unsigned)__builtin_bit_cast(unsigned short, (__bf16)p0) |
                       ((unsigned)__builtin_bit_cast(unsigned short, (__bf16)p1) << 16);
                wv.y = (unsigned)__builtin_bit_cast(unsigned short, (__bf16)p2) |
                       ((unsigned)__builtin_bit_cast(unsigned short, (__bf16)p3) << 16);
                *(uint2*)&ps[l16 * 64 + (((j * 2 + pwq) ^ x7) << 3) + pwh] = wv;
            }
        } else {
            const int kq = kb0 + quad * 4;
#pragma unroll
            for (int j = 0; j < 4; j++) {
                float p[4];
#pragma unroll
                for (int r = 0; r < 4; r++) {
                    p[r] = (kq + j * 16 + r < N_TOK) ? exp2f(sa[j][r] - m_l) : 0.f;
                    l_l += p[r];
                }
                uint2 wv;
                wv.x = (unsigned)__builtin_bit_cast(unsigned short, (__bf16)p[0]) |
                       ((unsigned)__builtin_bit_cast(unsigned short, (__bf16)p[1]) << 16);
                wv.y = (unsigned)__builtin_bit_cast(unsigned short, (__bf16)p[2]) |
                       ((unsigned)__builtin_bit_cast(unsigned short, (__bf16)p[3]) << 16);
                *(uint2*)&ps[l16 * 64 + (((j * 2 + pwq) ^ x7) << 3) + pwh] = wv;
            }
        }

        // ---- V(t) ready: drain all but K(t+1) (4 if issued, else 0); barrier
        if (has_next) { asm volatile("s_waitcnt vmcnt(4)" ::: "memory"); }
        else          { asm volatile("s_waitcnt vmcnt(0)" ::: "memory"); }
        __builtin_amdgcn_sched_barrier(0);
        __builtin_amdgcn_s_barrier();

        // ---- O += P V
        __builtin_amdgcn_s_setprio(1);
#pragma unroll
        for (int ks = 0; ks < 2; ks++) {
            bf16x8 ap = *(const bf16x8*)&ps[l16 * 64 + koff[ks]];
#pragma unroll
            for (int jd = 0; jd < 8; jd++) {
                bf16x8 bvf = *(const bf16x8*)&Vs[(jd * 16 + l16) * 64 + koff[ks]];
                oacc[jd] = MFMA(ap, bvf, oacc[jd]);
            }
        }
        __builtin_amdgcn_s_setprio(0);
        __builtin_amdgcn_s_barrier();            // all waves done reading Vs

        // ---- issue V(t+1) (lands while next tile does QK+softmax)
        if (has_next) {
            const int kn = kb0 + 64;
#pragma unroll
            for (int i = 0; i < 4; i++)
                gload_lds16(vsrc + (size_t)(32 * i) * VT_STRIDE + kn, &Vs[(tid + 256 * i) * 8]);
        }
    }

    // ---- reduce l partials across quads (lanes sharing l16), normalize, store
    l_l += __shfl_xor(l_l, 16);
    l_l += __shfl_xor(l_l, 32);
    const float inv = 1.f / l_l;                       // full softmax denom for row q0+l16

#pragma unroll
    for (int r = 0; r < 4; r++) {
        const float ir = __shfl(inv, quad * 4 + r, 16);  // denom of row q0+quad*4+r
        int rg = q0 + quad * 4 + r;
        if (rg < N_TOK) {
            unsigned short* orow = ab + (size_t)rg * DMODEL + head * HDIM;
#pragma unroll
            for (int jd = 0; jd < 8; jd++)
                orow[jd * 16 + l16] = f2bf(oacc[jd][r] * ir);
        }
    }
}

// ---------------------------------------------------------------------------
extern "C" void kernel_launch(void* const* d_in, const int* in_sizes, int n_in,
                              void* d_out, int out_size, void* d_ws, size_t ws_size,
                              hipStream_t stream) {
    const float* x   = (const float*)d_in[0];
    const float* Wq  = (const float*)d_in[1];
    const float* bq  = (const float*)d_in[2];
    const float* Wk  = (const float*)d_in[3];
    const float* bk  = (const float*)d_in[4];
    const float* Wv  = (const float*)d_in[5];
    const float* bv  = (const float*)d_in[6];
    const float* Wo  = (const float*)d_in[7];
    const float* bo  = (const float*)d_in[8];
    const float* qsc = (const float*)d_in[9];
    const float* ksc = (const float*)d_in[10];
    const float* ft  = (const float*)d_in[11];
    const float* fh  = (const float*)d_in[12];
    const float* fw  = (const float*)d_in[13];

    // Layout note: ab sits BEFORE the fp32 region so the O-GEMM's A-tile
    // over-reads (rows 2925..2943) land inside d_ws (vt data), never past end.
    // QKV-GEMM A-overreads (rows 2925..3071, 451KB) land in Wt — also safe.
    char* ws = (char*)d_ws;
    unsigned short* xb   = (unsigned short*)ws; ws += (size_t)N_TOK * DMODEL * 2;          // 8,985,600
    unsigned short* Wt   = (unsigned short*)ws; ws += (size_t)4 * DMODEL * DMODEL * 2;     // 18,874,368
    unsigned short* ab   = (unsigned short*)ws; ws += (size_t)N_TOK * DMODEL * 2;          // 8,985,600
    char* qkvf_region    = ws;                  ws += (size_t)3 * N_TOK * DMODEL * 4;      // 53,913,600
    unsigned short* qkvb = (unsigned short*)ws; ws += (size_t)2 * N_TOK * DMODEL * 2;      // 17,971,200

    // Phase 1: qkvf_region holds fp32 QKV projections (53.9 MB).
    float* Qf = (float*)qkvf_region;
    float* Kf = Qf + (size_t)N_TOK * DMODEL;
    float* Vf = Qf + (size_t)2 * N_TOK * DMODEL;
    // Phase 2 (after k_norm_rope): vt (9.04 MB) reuses the dead Qf space;
    // Vf (read by k_transpose_vf) is untouched by the vt writes.
    unsigned short* vtp = (unsigned short*)qkvf_region;

    unsigned short* qbp = qkvb;
    unsigned short* kbp = qkvb + (size_t)N_TOK * DMODEL;

    const int nelem = N_TOK * DMODEL;
    k_convert_x<<<(nelem / 4 + 255) / 256, 256, 0, stream>>>(x, xb, nelem);
    k_transpose_w<<<dim3(48, 48, 4), dim3(32, 8), 0, stream>>>(Wq, Wk, Wv, Wo, Wt);
    k_gemm_qkv<<<dim3(6, 12, 3), 512, 0, stream>>>(xb, Wt, bq, bk, bv, Qf, N_TOK);
    k_norm_rope<<<N_TOK, 256, 0, stream>>>(Qf, Kf, qsc, ksc, ft, fh, fw, qbp, kbp);
    k_transpose_vf<<<dim3(92, 4, NHEAD), dim3(32, 8), 0, stream>>>(Vf, vtp);
    k_attn_part<<<dim3(46, NHEAD), 256, 0, stream>>>(qbp, kbp, vtp, ab);
    k_gemm<<<dim3(12, 23, 1), 256, 0, stream>>>(ab, Wt + (size_t)3 * DMODEL * DMODEL,
                                                bo, bo, bo, (float*)d_out, N_TOK);
}

// Round 9
// 345.365 us; speedup vs baseline: 1.1407x; 1.0201x over previous
//
#include <hip/hip_runtime.h>

// ---------------------------------------------------------------------------
// MultiHeadAttention (B=1, N=2925, D_MODEL=1536, 12 heads x 128) on gfx950.
// prep(convert x + transpose W, merged) -> QKV bf16 GEMM (256x256 dbuf
// counted-vmcnt pipeline) -> postproj(RMSNorm+RoPE Q,K + V transpose, merged)
// -> NO-SPLIT flash attention (swapped-QK^T, phase-shifted staging, epilogue
// normalization) -> O GEMM (128^2).
// ---------------------------------------------------------------------------

#define N_TOK 2925
#define DMODEL 1536
#define NHEAD 12
#define HDIM 128
#define VT_STRIDE 2944        // N_TOK padded to x64; pad MUST be zeroed (NaN hazard)

typedef __attribute__((ext_vector_type(8))) __bf16 bf16x8;
typedef __attribute__((ext_vector_type(4))) float floatx4;

#define MFMA(a, b, c) __builtin_amdgcn_mfma_f32_16x16x32_bf16((a), (b), (c), 0, 0, 0)

static __device__ __forceinline__ unsigned short f2bf(float f) {
    unsigned u = __builtin_bit_cast(unsigned, f);
    return (unsigned short)((u + 0x7fffu + ((u >> 16) & 1u)) >> 16);
}

// async global->LDS 16B/lane (emits global_load_lds_dwordx4).
// LDS dest MUST be wave-uniform-base + lane*16.
static __device__ __forceinline__ void gload_lds16(const unsigned short* g, unsigned short* l) {
    __builtin_amdgcn_global_load_lds((const __attribute__((address_space(1))) void*)g,
                                     (__attribute__((address_space(3))) void*)l, 16, 0, 0);
}

// ------------------- merged prep: W transposes (blocks 0..9215) + x convert
// transpose_w: [k][n] fp32 -> [n][k] bf16 for Wq,Wk,Wv,Wo.
// convert_x: fp32 -> bf16, 4 elems/thread.
__global__ __launch_bounds__(256) void k_prep(const float* __restrict__ W0,
                                              const float* __restrict__ W1,
                                              const float* __restrict__ W2,
                                              const float* __restrict__ W3,
                                              unsigned short* __restrict__ Wt,
                                              const float* __restrict__ x,
                                              unsigned short* __restrict__ xb, int n) {
    const int b = blockIdx.x;
    if (b < 9216) {                                    // ---- transpose role
        __shared__ float tile[32][33];
        const int bz = b / 2304, rem = b % 2304;
        const int byi = rem / 48, bxi = rem % 48;
        const float* W = bz == 0 ? W0 : bz == 1 ? W1 : bz == 2 ? W2 : W3;
        unsigned short* out = Wt + (size_t)bz * DMODEL * DMODEL;
        const int tx = threadIdx.x & 31, ty = threadIdx.x >> 5;   // 32 x 8
        const int bx = bxi * 32, by = byi * 32;
#pragma unroll
        for (int i = 0; i < 4; i++)
            tile[ty + 8 * i][tx] = W[(size_t)(by + ty + 8 * i) * DMODEL + bx + tx];
        __syncthreads();
#pragma unroll
        for (int i = 0; i < 4; i++)
            out[(size_t)(bx + ty + 8 * i) * DMODEL + by + tx] = f2bf(tile[tx][ty + 8 * i]);
    } else {                                           // ---- convert role
        int i = ((b - 9216) * 256 + threadIdx.x) * 4;
        if (i < n) {
            float4 v = *(const float4*)(x + i);
            uint2 o;
            o.x = (unsigned)f2bf(v.x) | ((unsigned)f2bf(v.y) << 16);
            o.y = (unsigned)f2bf(v.z) | ((unsigned)f2bf(v.w) << 16);
            *(uint2*)(xb + i) = o;
        }
    }
}

// ---------------------- QKV GEMM: 256x256 tile, BK=64, 8 waves, dbuf pipeline
// LDS 128 KiB (2 bufs x (A,B) x 256x64 bf16), XOR swizzle chunk^=(row&7) on
// both sides.  Per K-tile 4 phases; staging spread {B-top,B-bot,A-lo,A-hi}
// (A halves interleaved).  Counted vmcnt(2) at W1/W2; raw s_barrier.
__global__ __launch_bounds__(512, 2) void k_gemm_qkv(const unsigned short* __restrict__ A,
                                                     const unsigned short* __restrict__ BtBase,
                                                     const float* __restrict__ b0,
                                                     const float* __restrict__ b1,
                                                     const float* __restrict__ b2,
                                                     float* __restrict__ Cbase, int M) {
    __shared__ __align__(16) unsigned short As[2][256 * 64];   // 2 x 32 KiB
    __shared__ __align__(16) unsigned short Bs[2][256 * 64];   // 2 x 32 KiB

    // XCD swizzle: nb = 216 = 8*27 exact
    const int blin = blockIdx.x + 6 * (blockIdx.y + 12 * (int)blockIdx.z);
    const int wg = (blin & 7) * 27 + (blin >> 3);
    const int z = wg / 72, rem = wg % 72, mt = rem / 6, ntile = rem % 6;
    const unsigned short* Bt = BtBase + (size_t)z * DMODEL * DMODEL;
    const float* bias = (z == 0) ? b0 : (z == 1) ? b1 : b2;
    float* C = Cbase + (size_t)z * M * DMODEL;
    const int m0 = mt * 256, n0 = ntile * 256;

    const int tid = threadIdx.x;
    const int wave = tid >> 6, lane = tid & 63, quad = lane >> 4, l16 = lane & 15;
    const int x7 = l16 & 7;
    const int wm = wave >> 2, wn = wave & 3;

    const int koff0 = ((quad) ^ x7) * 8;
    const int koff1 = ((4 + quad) ^ x7) * 8;
    const int sl = tid & 7;

    floatx4 acc[8][4] = {};

    const unsigned short* Abase = A + (size_t)m0 * DMODEL;
    const unsigned short* Bbase = Bt + (size_t)n0 * DMODEL;

    auto stageB = [&](int buf, int h, int kt) {
#pragma unroll
        for (int i = 0; i < 2; i++) {
            int d = tid + 512 * i;
            int row = h * 128 + (d >> 3);
            int c = sl ^ (row & 7);
            gload_lds16(Bbase + (size_t)row * DMODEL + kt * 64 + c * 8,
                        &Bs[buf][(row * 8 + sl) * 8]);
        }
    };
    auto stageA = [&](int buf, int h, int kt) {
#pragma unroll
        for (int i = 0; i < 2; i++) {
            int d = tid + 512 * i;
            int r7 = d >> 3;
            int row = (r7 & 63) + h * 64 + (r7 >> 6) * 128;
            int c = sl ^ (row & 7);
            gload_lds16(Abase + (size_t)row * DMODEL + kt * 64 + c * 8,
                        &As[buf][(row * 8 + sl) * 8]);
        }
    };

    stageB(0, 0, 0); stageB(0, 1, 0); stageA(0, 0, 0); stageA(0, 1, 0);

    const int NT = DMODEL / 64;                                  // 24
    for (int t = 0; t < NT; t++) {
        const int c = t & 1, sb = c ^ 1;
        const int ts = (t + 1 < NT) ? t + 1 : NT - 1;

        asm volatile("s_waitcnt vmcnt(2)" ::: "memory");
        __builtin_amdgcn_sched_barrier(0);
        __builtin_amdgcn_s_barrier();

        bf16x8 af[4], bfm[4];
#pragma unroll
        for (int m = 0; m < 4; m++)
            af[m] = *(const bf16x8*)&As[c][(wm * 128 + m * 16 + l16) * 64 + koff0];
#pragma unroll
        for (int n = 0; n < 4; n++)
            bfm[n] = *(const bf16x8*)&Bs[c][(wn * 64 + n * 16 + l16) * 64 + koff0];
        stageB(sb, 0, ts);
        __builtin_amdgcn_s_barrier();
        __builtin_amdgcn_s_setprio(1);
#pragma unroll
        for (int m = 0; m < 4; m++)
#pragma unroll
            for (int n = 0; n < 4; n++)
                acc[m][n] = MFMA(af[m], bfm[n], acc[m][n]);
        __builtin_amdgcn_s_setprio(0);
        __builtin_amdgcn_sched_barrier(0);

        asm volatile("s_waitcnt vmcnt(2)" ::: "memory");
        __builtin_amdgcn_sched_barrier(0);
        __builtin_amdgcn_s_barrier();

        bf16x8 af2[4];
#pragma unroll
        for (int m = 0; m < 4; m++)
            af2[m] = *(const bf16x8*)&As[c][(wm * 128 + 64 + m * 16 + l16) * 64 + koff0];
        stageB(sb, 1, ts);
        __builtin_amdgcn_s_barrier();
        __builtin_amdgcn_s_setprio(1);
#pragma unroll
        for (int m = 0; m < 4; m++)
#pragma unroll
            for (int n = 0; n < 4; n++)
                acc[4 + m][n] = MFMA(af2[m], bfm[n], acc[4 + m][n]);
        __builtin_amdgcn_s_setprio(0);
        __builtin_amdgcn_sched_barrier(0);

#pragma unroll
        for (int m = 0; m < 4; m++)
            af[m] = *(const bf16x8*)&As[c][(wm * 128 + m * 16 + l16) * 64 + koff1];
#pragma unroll
        for (int n = 0; n < 4; n++)
            bfm[n] = *(const bf16x8*)&Bs[c][(wn * 64 + n * 16 + l16) * 64 + koff1];
        stageA(sb, 0, ts);
        __builtin_amdgcn_s_barrier();
        __builtin_amdgcn_s_setprio(1);
#pragma unroll
        for (int m = 0; m < 4; m++)
#pragma unroll
            for (int n = 0; n < 4; n++)
                acc[m][n] = MFMA(af[m], bfm[n], acc[m][n]);
        __builtin_amdgcn_s_setprio(0);
        __builtin_amdgcn_sched_barrier(0);

#pragma unroll
        for (int m = 0; m < 4; m++)
            af2[m] = *(const bf16x8*)&As[c][(wm * 128 + 64 + m * 16 + l16) * 64 + koff1];
        stageA(sb, 1, ts);
        __builtin_amdgcn_s_barrier();
        __builtin_amdgcn_s_setprio(1);
#pragma unroll
        for (int m = 0; m < 4; m++)
#pragma unroll
            for (int n = 0; n < 4; n++)
                acc[4 + m][n] = MFMA(af2[m], bfm[n], acc[4 + m][n]);
        __builtin_amdgcn_s_setprio(0);
        __builtin_amdgcn_sched_barrier(0);
    }

#pragma unroll
    for (int n = 0; n < 4; n++) {
        int cg = n0 + wn * 64 + n * 16 + l16;
        float bv = bias[cg];
#pragma unroll
        for (int m = 0; m < 8; m++) {
            int rbase = m0 + wm * 128 + m * 16 + quad * 4;
#pragma unroll
            for (int r = 0; r < 4; r++) {
                int rg = rbase + r;
                if (rg < M) C[(size_t)rg * DMODEL + cg] = acc[m][n][r] + bv;
            }
        }
    }
}

// ------------------------------------------------------------ bf16 MFMA GEMM
// m97 structure (used for the O projection): unpadded stride-32 LDS tiles.
__global__ __launch_bounds__(256, 3) void k_gemm(const unsigned short* __restrict__ A,
                                                 const unsigned short* __restrict__ BtBase,
                                                 const float* __restrict__ b0,
                                                 const float* __restrict__ b1,
                                                 const float* __restrict__ b2,
                                                 float* __restrict__ Cbase, int M) {
    const int nbx = gridDim.x, nxy = gridDim.x * gridDim.y;
    const int nb = nxy * gridDim.z;
    const int blin = blockIdx.x + nbx * (blockIdx.y + gridDim.y * blockIdx.z);
    const int q8 = nb >> 3, r8 = nb & 7, xcd = blin & 7, idx = blin >> 3;
    const int wg = (xcd < r8) ? xcd * (q8 + 1) + idx
                              : r8 * (q8 + 1) + (xcd - r8) * q8 + idx;
    const int z = wg / nxy;
    const int rem = wg % nxy;
    const int bym = rem / nbx, bxn = rem % nbx;

    const unsigned short* Bt = BtBase + (size_t)z * DMODEL * DMODEL;
    const float* bias = (z == 0) ? b0 : (z == 1) ? b1 : b2;
    float* C = Cbase + (size_t)z * M * DMODEL;

    __shared__ __align__(16) unsigned short As[128 * 32];
    __shared__ __align__(16) unsigned short Bs[128 * 32];

    const int tid = threadIdx.x;
    const int wave = tid >> 6, lane = tid & 63, quad = lane >> 4, l16 = lane & 15;
    const int wr = wave >> 1, wc = wave & 1;
    const int m0 = bym * 128, n0 = bxn * 128;
    const int r4 = tid >> 2, c4 = (tid & 3) * 8;

    floatx4 acc[4][4] = {};

    for (int k0 = 0; k0 < DMODEL; k0 += 32) {
        gload_lds16(A + (size_t)(m0 + r4) * DMODEL + k0 + c4,       &As[r4 * 32 + c4]);
        gload_lds16(A + (size_t)(m0 + r4 + 64) * DMODEL + k0 + c4,  &As[(r4 + 64) * 32 + c4]);
        gload_lds16(Bt + (size_t)(n0 + r4) * DMODEL + k0 + c4,      &Bs[r4 * 32 + c4]);
        gload_lds16(Bt + (size_t)(n0 + r4 + 64) * DMODEL + k0 + c4, &Bs[(r4 + 64) * 32 + c4]);
        __syncthreads();

        bf16x8 af[4], bfm[4];
#pragma unroll
        for (int i = 0; i < 4; i++)
            af[i] = *(const bf16x8*)&As[(wr * 64 + i * 16 + l16) * 32 + quad * 8];
#pragma unroll
        for (int j = 0; j < 4; j++)
            bfm[j] = *(const bf16x8*)&Bs[(wc * 64 + j * 16 + l16) * 32 + quad * 8];
#pragma unroll
        for (int i = 0; i < 4; i++)
#pragma unroll
            for (int j = 0; j < 4; j++)
                acc[i][j] = MFMA(af[i], bfm[j], acc[i][j]);
        __syncthreads();
    }

#pragma unroll
    for (int j = 0; j < 4; j++) {
        int cg = n0 + wc * 64 + j * 16 + l16;
        float bv = bias[cg];
#pragma unroll
        for (int i = 0; i < 4; i++) {
            int rbase = m0 + wr * 64 + i * 16 + quad * 4;
#pragma unroll
            for (int r = 0; r < 4; r++) {
                int rg = rbase + r;
                if (rg < M) C[(size_t)rg * DMODEL + cg] = acc[i][j][r] + bv;
            }
        }
    }
}

// ---------- merged postproj: RMSNorm+3D RoPE (blocks 0..2924) + V transpose
// norm: q pre-scaled by (1/sqrt(HDIM))*log2(e) -> exp2-domain softmax.
// V transpose: Vf fp32 [tok][1536] -> vt bf16 [head][128][VT_STRIDE],
// pad columns [N_TOK, VT_STRIDE) WRITTEN AS ZERO (recycled region NaN hazard).
__global__ __launch_bounds__(256) void k_postproj(const float* __restrict__ Qf,
                                                  const float* __restrict__ Kf,
                                                  const float* __restrict__ Vf,
                                                  const float* __restrict__ qsc,
                                                  const float* __restrict__ ksc,
                                                  const float* __restrict__ ft,
                                                  const float* __restrict__ fh,
                                                  const float* __restrict__ fw,
                                                  unsigned short* __restrict__ qb,
                                                  unsigned short* __restrict__ kb,
                                                  unsigned short* __restrict__ vt) {
    const int blk = blockIdx.x;
    if (blk >= N_TOK) {                                // ---- V transpose role
        __shared__ float tile[32][33];
        const int v = blk - N_TOK;                     // 0..4415
        const int bxi = v % 92, byi = (v / 92) % 4, head = v / 368;
        const int t0 = bxi * 32, d0 = byi * 32;
        const int tx = threadIdx.x & 31, ty = threadIdx.x >> 5;   // 32 x 8
#pragma unroll
        for (int i = 0; i < 4; i++) {
            int t = t0 + ty + 8 * i;
            tile[ty + 8 * i][tx] = (t < N_TOK) ? Vf[(size_t)t * DMODEL + head * HDIM + d0 + tx] : 0.f;
        }
        __syncthreads();
        int t = t0 + tx;                               // < VT_STRIDE always
#pragma unroll
        for (int i = 0; i < 4; i++)
            vt[((size_t)head * HDIM + d0 + ty + 8 * i) * VT_STRIDE + t] = f2bf(tile[tx][ty + 8 * i]);
        return;
    }

    // ---- norm+rope role
    const int n = blk;
    const int tid = threadIdx.x, wave = tid >> 6, lane = tid & 63;
    const int t_i = n / 225, rem = n % 225, h_i = rem / 15, w_i = rem % 15;
    const float att_scale = 0.08838834764831845f * 1.4426950408889634f;  // 1/sqrt(128)*log2e

    float2 qv[3], kv[3];
    float sq = 0.f, sk = 0.f;
#pragma unroll
    for (int c = 0; c < 3; c++) {
        int p = tid + 256 * c;
        qv[c] = *(const float2*)(Qf + (size_t)n * DMODEL + 2 * p);
        kv[c] = *(const float2*)(Kf + (size_t)n * DMODEL + 2 * p);
        sq += qv[c].x * qv[c].x + qv[c].y * qv[c].y;
        sk += kv[c].x * kv[c].x + kv[c].y * kv[c].y;
    }
#pragma unroll
    for (int off = 32; off >= 1; off >>= 1) {
        sq += __shfl_xor(sq, off, 64);
        sk += __shfl_xor(sk, off, 64);
    }
    __shared__ float red[2][4];
    if (lane == 0) { red[0][wave] = sq; red[1][wave] = sk; }
    __syncthreads();
    sq = red[0][0] + red[0][1] + red[0][2] + red[0][3];
    sk = red[1][0] + red[1][1] + red[1][2] + red[1][3];
    const float rq = rsqrtf(sq * (1.f / 1536.f) + 1e-6f) * att_scale;
    const float rk = rsqrtf(sk * (1.f / 1536.f) + 1e-6f);

#pragma unroll
    for (int c = 0; c < 3; c++) {
        int p = tid + 256 * c;
        int hd = p >> 6, pl = p & 63, dd = 2 * pl;
        float cs, sn;
        if (pl < 22)      { cs = ft[t_i * 44 + 2 * pl];        sn = ft[t_i * 44 + 2 * pl + 1]; }
        else if (pl < 43) { int pp = pl - 22; cs = fh[h_i * 42 + 2 * pp]; sn = fh[h_i * 42 + 2 * pp + 1]; }
        else              { int pp = pl - 43; cs = fw[w_i * 42 + 2 * pp]; sn = fw[w_i * 42 + 2 * pp + 1]; }
        int hidx = hd * 128 + dd;
        float q0 = qv[c].x * rq * qsc[hidx], q1 = qv[c].y * rq * qsc[hidx + 1];
        float k0 = kv[c].x * rk * ksc[hidx], k1 = kv[c].y * rk * ksc[hidx + 1];
        size_t o = ((size_t)hd * N_TOK + n) * HDIM + dd;
        unsigned qo = (unsigned)f2bf(q0 * cs - q1 * sn) | ((unsigned)f2bf(q0 * sn + q1 * cs) << 16);
        unsigned ko = (unsigned)f2bf(k0 * cs - k1 * sn) | ((unsigned)f2bf(k0 * sn + k1 * cs) << 16);
        *(unsigned*)(qb + o) = qo;
        *(unsigned*)(kb + o) = ko;
    }
}

// ---------------- NO-SPLIT flash attention, phase-shifted async pipeline (R8)
// Block = (q-tile 64 rows, head). 4 waves x 16 rows each. 46 KV tiles of 64.
// exp2-domain softmax (log2e folded into q).  Swapped QK^T: sa[j][r] =
// S[qrow=l16][key=j*16+quad*4+r] -> lane-local softmax, b64 P writes.
// Epilogue: normalize by 1/l and write bf16 ab directly (no combine pass).
//
// Pipeline (counted vmcnt, raw barriers):
//   top:   vmcnt(4) [drain Q+K(t), V(t) in flight] ; barrier ; QK
//   post-QK barrier ; issue K(t+1)
//   pre-PV: vmcnt(4) [drain V(t), K(t+1) in flight] ; barrier ; PV
//   post-PV barrier ; issue V(t+1)
// XCD swizzle: 552 blocks = 8 x 69 (exact).
// LDS = 16384 (K) + 16384 (V^T) + 8192 (P) = 40960 -> 4 blocks/CU.
__global__ __launch_bounds__(256, 4) void k_attn_part(const unsigned short* __restrict__ qb,
                                                      const unsigned short* __restrict__ kb,
                                                      const unsigned short* __restrict__ vt,
                                                      unsigned short* __restrict__ ab) {
    __shared__ __align__(16) unsigned short Ks[64 * 128];   // [key][d]   linear+swz
    __shared__ __align__(16) unsigned short Vs[128 * 64];   // [d][key]   linear+swz
    __shared__ __align__(16) unsigned short Ps[4][16 * 64]; // per-wave P [qrow][key] swz

    // XCD-aware remap (bijective: 552 = 8*69)
    const int b = blockIdx.x + 46 * (int)blockIdx.y;
    const int w = (b & 7) * 69 + (b >> 3);
    const int qblk = w % 46;
    const int head = w / 46;

    const int tid = threadIdx.x, wave = tid >> 6, lane = tid & 63;
    const int quad = lane >> 4, l16 = lane & 15, x7 = l16 & 7;
    const int q0 = qblk * 64 + wave * 16;
    const unsigned short* qh = qb + (size_t)head * N_TOK * HDIM;
    const unsigned short* kh = kb + (size_t)head * N_TOK * HDIM;
    const unsigned short* vh = vt + (size_t)head * HDIM * VT_STRIDE;
    unsigned short* ps = Ps[wave];

    const int ntile = (N_TOK + 63) >> 6;               // 46 (last tile partial: 45 keys)

    int koff[4];
#pragma unroll
    for (int ks = 0; ks < 4; ks++) {
        int c = ks * 4 + quad;
        koff[ks] = ((c & 8) | ((c & 7) ^ x7)) * 8;
    }
    const int pwq = (quad >> 1), pwh = (quad & 1) * 4;

    const int krow = tid >> 4, ksw = tid & 15;
    const int kc = (ksw & 8) | ((ksw & 7) ^ (krow & 7));   // (krow+16i)&7 == krow&7
    const int vd = tid >> 3, vsw = tid & 7;
    const int vc = vsw ^ (vd & 7);                          // (vd+32i)&7 == vd&7
    const unsigned short* ksrc = kh + (size_t)krow * HDIM + kc * 8;
    const unsigned short* vsrc = vh + (size_t)vd * VT_STRIDE + vc * 8;

    bf16x8 aq[4];
    {
        int qrow = q0 + l16;
        if (qrow < N_TOK) {
#pragma unroll
            for (int ks = 0; ks < 4; ks++)
                aq[ks] = *(const bf16x8*)&qh[(size_t)qrow * HDIM + ks * 32 + quad * 8];
        } else {
#pragma unroll
            for (int ks = 0; ks < 4; ks++) aq[ks] = (bf16x8)(__bf16)0.0f;
        }
    }

    floatx4 oacc[8] = {};
    float m_l = -1e30f;
    float l_l = 0.f;

    // ---- prologue: issue K(0) then V(0)  (tile 0 is always full)
#pragma unroll
    for (int i = 0; i < 4; i++)
        gload_lds16(ksrc + (size_t)(16 * i) * HDIM, &Ks[(tid + 256 * i) * 8]);
#pragma unroll
    for (int i = 0; i < 4; i++)
        gload_lds16(vsrc + (size_t)(32 * i) * VT_STRIDE, &Vs[(tid + 256 * i) * 8]);

    for (int t = 0; t < ntile; t++) {
        const int kb0 = t * 64;
        const bool fullt = (kb0 + 64 <= N_TOK);        // false only for t=45
        const bool has_next = (t + 1 < ntile);

        asm volatile("s_waitcnt vmcnt(4)" ::: "memory");
        __builtin_amdgcn_sched_barrier(0);
        __builtin_amdgcn_s_barrier();

        floatx4 sa[4] = {};
        __builtin_amdgcn_s_setprio(1);
#pragma unroll
        for (int j = 0; j < 4; j++)
#pragma unroll
            for (int ks = 0; ks < 4; ks++) {
                bf16x8 bkf = *(const bf16x8*)&Ks[(j * 16 + l16) * HDIM + koff[ks]];
                sa[j] = MFMA(bkf, aq[ks], sa[j]);
            }
        __builtin_amdgcn_s_setprio(0);
        __builtin_amdgcn_s_barrier();            // all waves done reading Ks

        if (has_next) {
            const int kn = kb0 + 64;
            if (kn + 64 <= N_TOK) {
#pragma unroll
                for (int i = 0; i < 4; i++)
                    gload_lds16(ksrc + (size_t)(kn + 16 * i) * HDIM, &Ks[(tid + 256 * i) * 8]);
            } else {
#pragma unroll
                for (int i = 0; i < 4; i++) {
                    int gk = kn + krow + 16 * i;
                    gk = gk < N_TOK ? gk : N_TOK - 1;
                    gload_lds16(kh + (size_t)gk * HDIM + kc * 8, &Ks[(tid + 256 * i) * 8]);
                }
            }
        }

        float mt;
        if (fullt) {
            float m01 = fmaxf(fmaxf(sa[0][0], sa[0][1]), fmaxf(sa[0][2], sa[0][3]));
            float m23 = fmaxf(fmaxf(sa[1][0], sa[1][1]), fmaxf(sa[1][2], sa[1][3]));
            float m45 = fmaxf(fmaxf(sa[2][0], sa[2][1]), fmaxf(sa[2][2], sa[2][3]));
            float m67 = fmaxf(fmaxf(sa[3][0], sa[3][1]), fmaxf(sa[3][2], sa[3][3]));
            mt = fmaxf(fmaxf(m01, m23), fmaxf(m45, m67));
        } else {
            mt = -1e30f;
            const int kq = kb0 + quad * 4;
#pragma unroll
            for (int j = 0; j < 4; j++)
#pragma unroll
                for (int r = 0; r < 4; r++)
                    mt = fmaxf(mt, (kq + j * 16 + r < N_TOK) ? sa[j][r] : -1e30f);
        }
        mt = fmaxf(mt, __shfl_xor(mt, 16));
        mt = fmaxf(mt, __shfl_xor(mt, 32));

        if (__any(mt > m_l + 8.f)) {
            float mn = fmaxf(m_l, mt);
            float alpha = exp2f(m_l - mn);
            m_l = mn;
            l_l *= alpha;
#pragma unroll
            for (int r = 0; r < 4; r++) {
                float ar = __shfl(alpha, quad * 4 + r, 16);
#pragma unroll
                for (int jd = 0; jd < 8; jd++) oacc[jd][r] *= ar;
            }
        }

        if (fullt) {
#pragma unroll
            for (int j = 0; j < 4; j++) {
                float p0 = exp2f(sa[j][0] - m_l), p1 = exp2f(sa[j][1] - m_l);
                float p2 = exp2f(sa[j][2] - m_l), p3 = exp2f(sa[j][3] - m_l);
                l_l += (p0 + p1) + (p2 + p3);
                uint2 wv;
                wv.x = (unsigned)__builtin_bit_cast(unsigned short, (__bf16)p0) |
                       ((unsigned)__builtin_bit_cast(unsigned short, (__bf16)p1) << 16);
                wv.y = (unsigned)__builtin_bit_cast(unsigned short, (__bf16)p2) |
                       ((unsigned)__builtin_bit_cast(unsigned short, (__bf16)p3) << 16);
                *(uint2*)&ps[l16 * 64 + (((j * 2 + pwq) ^ x7) << 3) + pwh] = wv;
            }
        } else {
            const int kq = kb0 + quad * 4;
#pragma unroll
            for (int j = 0; j < 4; j++) {
                float p[4];
#pragma unroll
                for (int r = 0; r < 4; r++) {
                    p[r] = (kq + j * 16 + r < N_TOK) ? exp2f(sa[j][r] - m_l) : 0.f;
                    l_l += p[r];
                }
                uint2 wv;
                wv.x = (unsigned)__builtin_bit_cast(unsigned short, (__bf16)p[0]) |
                       ((unsigned)__builtin_bit_cast(unsigned short, (__bf16)p[1]) << 16);
                wv.y = (unsigned)__builtin_bit_cast(unsigned short, (__bf16)p[2]) |
                       ((unsigned)__builtin_bit_cast(unsigned short, (__bf16)p[3]) << 16);
                *(uint2*)&ps[l16 * 64 + (((j * 2 + pwq) ^ x7) << 3) + pwh] = wv;
            }
        }

        if (has_next) { asm volatile("s_waitcnt vmcnt(4)" ::: "memory"); }
        else          { asm volatile("s_waitcnt vmcnt(0)" ::: "memory"); }
        __builtin_amdgcn_sched_barrier(0);
        __builtin_amdgcn_s_barrier();

        __builtin_amdgcn_s_setprio(1);
#pragma unroll
        for (int ks = 0; ks < 2; ks++) {
            bf16x8 ap = *(const bf16x8*)&ps[l16 * 64 + koff[ks]];
#pragma unroll
            for (int jd = 0; jd < 8; jd++) {
                bf16x8 bvf = *(const bf16x8*)&Vs[(jd * 16 + l16) * 64 + koff[ks]];
                oacc[jd] = MFMA(ap, bvf, oacc[jd]);
            }
        }
        __builtin_amdgcn_s_setprio(0);
        __builtin_amdgcn_s_barrier();            // all waves done reading Vs

        if (has_next) {
            const int kn = kb0 + 64;
#pragma unroll
            for (int i = 0; i < 4; i++)
                gload_lds16(vsrc + (size_t)(32 * i) * VT_STRIDE + kn, &Vs[(tid + 256 * i) * 8]);
        }
    }

    // ---- reduce l partials across quads (lanes sharing l16), normalize, store
    l_l += __shfl_xor(l_l, 16);
    l_l += __shfl_xor(l_l, 32);
    const float inv = 1.f / l_l;                       // full softmax denom for row q0+l16

#pragma unroll
    for (int r = 0; r < 4; r++) {
        const float ir = __shfl(inv, quad * 4 + r, 16);  // denom of row q0+quad*4+r
        int rg = q0 + quad * 4 + r;
        if (rg < N_TOK) {
            unsigned short* orow = ab + (size_t)rg * DMODEL + head * HDIM;
#pragma unroll
            for (int jd = 0; jd < 8; jd++)
                orow[jd * 16 + l16] = f2bf(oacc[jd][r] * ir);
        }
    }
}

// ---------------------------------------------------------------------------
extern "C" void kernel_launch(void* const* d_in, const int* in_sizes, int n_in,
                              void* d_out, int out_size, void* d_ws, size_t ws_size,
                              hipStream_t stream) {
    const float* x   = (const float*)d_in[0];
    const float* Wq  = (const float*)d_in[1];
    const float* bq  = (const float*)d_in[2];
    const float* Wk  = (const float*)d_in[3];
    const float* bk  = (const float*)d_in[4];
    const float* Wv  = (const float*)d_in[5];
    const float* bv  = (const float*)d_in[6];
    const float* Wo  = (const float*)d_in[7];
    const float* bo  = (const float*)d_in[8];
    const float* qsc = (const float*)d_in[9];
    const float* ksc = (const float*)d_in[10];
    const float* ft  = (const float*)d_in[11];
    const float* fh  = (const float*)d_in[12];
    const float* fw  = (const float*)d_in[13];

    // Layout note: ab sits BEFORE the fp32 region so the O-GEMM's A-tile
    // over-reads (rows 2925..2943) land inside d_ws (vt data), never past end.
    // QKV-GEMM A-overreads (rows 2925..3071, 451KB) land in Wt — also safe.
    char* ws = (char*)d_ws;
    unsigned short* xb   = (unsigned short*)ws; ws += (size_t)N_TOK * DMODEL * 2;          // 8,985,600
    unsigned short* Wt   = (unsigned short*)ws; ws += (size_t)4 * DMODEL * DMODEL * 2;     // 18,874,368
    unsigned short* ab   = (unsigned short*)ws; ws += (size_t)N_TOK * DMODEL * 2;          // 8,985,600
    char* qkvf_region    = ws;                  ws += (size_t)3 * N_TOK * DMODEL * 4;      // 53,913,600
    unsigned short* qkvb = (unsigned short*)ws; ws += (size_t)2 * N_TOK * DMODEL * 2;      // 17,971,200

    // Phase 1: qkvf_region holds fp32 QKV projections (53.9 MB).
    float* Qf = (float*)qkvf_region;
    float* Kf = Qf + (size_t)N_TOK * DMODEL;
    float* Vf = Qf + (size_t)2 * N_TOK * DMODEL;
    // Phase 2 (after k_postproj): vt (9.04 MB) reuses the dead Qf space;
    // Vf (read by the transpose role) is untouched by the vt writes.
    unsigned short* vtp = (unsigned short*)qkvf_region;

    unsigned short* qbp = qkvb;
    unsigned short* kbp = qkvb + (size_t)N_TOK * DMODEL;

    const int nelem = N_TOK * DMODEL;
    const int conv_blocks = (nelem / 4 + 255) / 256;                 // 4393
    k_prep<<<9216 + conv_blocks, 256, 0, stream>>>(Wq, Wk, Wv, Wo, Wt, x, xb, nelem);
    k_gemm_qkv<<<dim3(6, 12, 3), 512, 0, stream>>>(xb, Wt, bq, bk, bv, Qf, N_TOK);
    k_postproj<<<N_TOK + 4416, 256, 0, stream>>>(Qf, Kf, Vf, qsc, ksc, ft, fh, fw,
                                                 qbp, kbp, vtp);
    k_attn_part<<<dim3(46, NHEAD), 256, 0, stream>>>(qbp, kbp, vtp, ab);
    k_gemm<<<dim3(12, 23, 1), 256, 0, stream>>>(ab, Wt + (size_t)3 * DMODEL * DMODEL,
                                                bo, bo, bo, (float*)d_out, N_TOK);
}